// Round 4
// baseline (651.890 us; speedup 1.0000x reference)
//
#include <hip/hip_runtime.h>

#define BATCH 4
#define NFEAT 64
#define DGRP 8
#define HH 96
#define WW 96
#define HWP (HH*WW)

typedef short short4a __attribute__((ext_vector_type(4)));
typedef short short8 __attribute__((ext_vector_type(8)));
typedef float f32x4 __attribute__((ext_vector_type(4)));
typedef float f32x16 __attribute__((ext_vector_type(16)));

__device__ inline short f2bf(float f) {
  union { float f; unsigned u; } v; v.f = f;
  unsigned r = v.u + 0x7fff + ((v.u >> 16) & 1);
  return (short)(r >> 16);
}
__device__ inline float bf2f(short s) {
  return __uint_as_float(((unsigned)(unsigned short)s) << 16);
}

// ---------------------------------------------------------------------------
// om-weight prep, 32x32 MFMA-A-fragment-shuffled (proven R6).
// ---------------------------------------------------------------------------
__global__ __launch_bounds__(256) void prep_om(
    const float* __restrict__ s0, const float* __restrict__ s1,
    const float* __restrict__ s2, const float* __restrict__ s3,
    short* __restrict__ dst) {
  int gid = blockIdx.x * 256 + threadIdx.x;
  if (gid >= 4 * 147456) return;
  int t = gid / 147456, r = gid % 147456;
  int tile = r / 18432, r2 = r % 18432;
  int kk = r2 / 512, r3 = r2 % 512;
  int lane = r3 / 8, j = r3 % 8;
  int col = lane & 31, half = lane >> 5;
  int oc = tile * 32 + col;
  int k = kk * 16 + half * 8 + j;
  int p = k >> 6, c = k & 63;
  const float* s = (t == 0) ? s0 : (t == 1) ? s1 : (t == 2) ? s2 : s3;
  float v = (oc < 216) ? s[(size_t)oc * 576 + c * 9 + p] : 0.f;
  dst[gid] = f2bf(v);
}

// ---------------------------------------------------------------------------
// dcn-weight prep, same 32x32 A-shuffle: dst[t][tile(2)][kk(36)][lane][8].
// ---------------------------------------------------------------------------
__global__ __launch_bounds__(256) void prep_dcnw(
    const float* __restrict__ s0, const float* __restrict__ s1,
    const float* __restrict__ s2, const float* __restrict__ s3,
    short* __restrict__ dst) {
  int gid = blockIdx.x * 256 + threadIdx.x;
  if (gid >= 4 * 36864) return;
  int t = gid / 36864, r = gid % 36864;
  int tile = r / 18432, r2 = r % 18432;
  int kk = r2 / 512, r3 = r2 % 512;
  int lane = r3 / 8, j = r3 % 8;
  int col = lane & 31, half = lane >> 5;
  int oc = tile * 32 + col;
  int k = kk * 16 + half * 8 + j;
  int p = k >> 6, c = k & 63;
  const float* s = (t == 0) ? s0 : (t == 1) ? s1 : (t == 2) ? s2 : s3;
  dst[gid] = f2bf(s[(size_t)oc * 576 + c * 9 + p]);
}

// ---------------------------------------------------------------------------
// gconv weight prep (proven R7): 16x16x32 A frags, group-pair block-diagonal.
// ---------------------------------------------------------------------------
struct GwArgs {
  const float* src[12];
  int cat[12];
  int base[13];
};

__global__ __launch_bounds__(256) void prep_gw(GwArgs a, short* __restrict__ dst) {
  int gid = blockIdx.x * 256 + threadIdx.x;
  if (gid >= a.base[12]) return;
  int t = 0;
  while (gid >= a.base[t + 1]) ++t;
  int r = gid - a.base[t];
  const float* s = a.src[t];
  const int tsz = a.cat[t] ? 4608 : 2560;
  int tile = r / tsz, r2 = r % tsz;
  int kk = r2 / 512, r3 = r2 % 512;
  int lane = r3 >> 3, j = r3 & 7;
  int m = lane & 15, quad = lane >> 4;
  int oc = tile * 16 + m;
  int j32 = quad * 8 + j;
  float val = 0.f;
  if (a.cat[t]) {
    int gsel = j32 >> 4, ssel = (j32 >> 3) & 1, ch8 = j32 & 7;
    if (gsel == (m >> 3)) val = s[oc * 144 + (2 * ch8 + ssel) * 9 + kk];
  } else {
    int tapsel = j32 >> 4, gsel = (j32 >> 3) & 1, ch8 = j32 & 7;
    int p = 2 * kk + tapsel;
    if (p < 9 && gsel == (m >> 3)) val = s[oc * 72 + ch8 * 9 + p];
  }
  dst[gid] = f2bf(val);
}

// ---------------------------------------------------------------------------
// Channel-major fp32 -> pixel-major bf16; z picks (nbr->nbrT, ref->refT).
// ---------------------------------------------------------------------------
__global__ __launch_bounds__(256) void transpose_bf16(
    const float* __restrict__ in0, short* __restrict__ out0,
    const float* __restrict__ in1, short* __restrict__ out1) {
  const float* in = blockIdx.z ? in1 : in0;
  short* out = blockIdx.z ? out1 : out0;
  __shared__ float s[64][65];
  const int p0 = blockIdx.x * 64;
  const int b = blockIdx.y;
  const int tx = threadIdx.x, ty = threadIdx.y;
  for (int c = ty; c < 64; c += 4)
    s[c][tx] = in[((size_t)b * NFEAT + c) * HWP + p0 + tx];
  __syncthreads();
  for (int p = ty; p < 64; p += 4)
    out[((size_t)b * HWP + p0 + p) * NFEAT + tx] = f2bf(s[tx][p]);
}

// ---------------------------------------------------------------------------
// Grouped 3x3 conv on 16x16x32 MFMA — R7 direct-load version (proven best).
// ---------------------------------------------------------------------------
template <bool CAT, bool LRELU>
__device__ __forceinline__ void gconv_body(
    const short* __restrict__ in0, const short* __restrict__ in1,
    const short* __restrict__ Wsh, const float* __restrict__ bias,
    short* __restrict__ out, int pixbase, int b) {
  const int lane = threadIdx.x, t = threadIdx.y;
  const int n = lane & 15, quad = lane >> 4;
  constexpr int NKK = CAT ? 9 : 5;

  short8 A[NKK];
#pragma unroll
  for (int kk = 0; kk < NKK; ++kk)
    A[kk] = *(const short8*)(Wsh + ((size_t)(t * NKK + kk) * 64 + lane) * 8);

  const short* sb;
  if (CAT) {
    sb = ((quad & 1) ? in1 : in0) + (size_t)b * HWP * 64 + (2 * t + (quad >> 1)) * 8;
  } else {
    sb = in0 + (size_t)b * HWP * 64 + (2 * t + (quad & 1)) * 8;
  }

  f32x4 acc[2] = {};
#pragma unroll
  for (int nt = 0; nt < 2; ++nt) {
    const int pix = pixbase + nt * 16 + n;
    const int yp = pix / WW, xp = pix % WW;
#pragma unroll
    for (int kk = 0; kk < NKK; ++kk) {
      const int p = CAT ? kk : (2 * kk + (quad >> 1));
      short8 B = {0, 0, 0, 0, 0, 0, 0, 0};
      if (p < 9) {
        const int sy = yp + p / 3 - 1, sx = xp + p % 3 - 1;
        if (((unsigned)sy < (unsigned)HH) && ((unsigned)sx < (unsigned)WW))
          B = *(const short8*)(sb + (size_t)(sy * WW + sx) * 64);
      }
      acc[nt] = __builtin_amdgcn_mfma_f32_16x16x32_bf16(A[kk], B, acc[nt], 0, 0, 0);
    }
  }

  const int ocb = t * 16 + quad * 4;
  const float b0 = bias[ocb], b1 = bias[ocb + 1], b2 = bias[ocb + 2], b3 = bias[ocb + 3];
#pragma unroll
  for (int nt = 0; nt < 2; ++nt) {
    float v0 = acc[nt][0] + b0, v1 = acc[nt][1] + b1;
    float v2 = acc[nt][2] + b2, v3 = acc[nt][3] + b3;
    if (LRELU) {
      v0 = (v0 >= 0.f) ? v0 : 0.1f * v0;
      v1 = (v1 >= 0.f) ? v1 : 0.1f * v1;
      v2 = (v2 >= 0.f) ? v2 : 0.1f * v2;
      v3 = (v3 >= 0.f) ? v3 : 0.1f * v3;
    }
    short4a pk = {f2bf(v0), f2bf(v1), f2bf(v2), f2bf(v3)};
    *(short4a*)(out + ((size_t)b * HWP + pixbase + nt * 16 + n) * 64 + ocb) = pk;
  }
}

template <bool CAT, bool LRELU>
__global__ __launch_bounds__(256) void gconv_mfma(
    const short* __restrict__ in0, const short* __restrict__ in1,
    const short* __restrict__ Wsh, const float* __restrict__ bias,
    short* __restrict__ out) {
  gconv_body<CAT, LRELU>(in0, in1, Wsh, bias, out, blockIdx.x * 32, blockIdx.y);
}

// Merged dispatch for the 3 independent oc1 convs (all CAT+LRELU).
struct Oc1Args {
  const short* W[3];
  const float* bias[3];
  short* out[3];
};

__global__ __launch_bounds__(256) void gconv_oc1x3(
    const short* __restrict__ in0, const short* __restrict__ in1, Oc1Args a) {
  const int job = blockIdx.z;
  gconv_body<true, true>(in0, in1, a.W[job], a.bias[job], a.out[job],
                         blockIdx.x * 32, blockIdx.y);
}

// ---------------------------------------------------------------------------
// Fused om-conv + DCN, R11: 8-wave critical-path-split version.
// R10 post-mortem: grid-limited (4608 waves chip-wide) + long per-wave serial
// chains; occupancy up, dur flat.  R11: 512-thread blocks (8 waves), every
// phase split 2x finer:
//   A: wave w owns ONE oc-tile (36 MFMA, single acc chain)  [was 2 tiles]
//   B: ty=(taphalf,dg): each thread samples 4-5 taps        [was 9]
//   C: K split 4-way (kh 0..3, 9 kk each) + 3-partial LDS reduce [was 2-way]
// Ls holds all 36 kk (no chunking; 4 barriers total).
// LDS = 36864 (Ls) + 13824 (om) = 50688 -> 3 blocks/CU = 24 waves/CU.
// Grid (288, BATCH), block (32, 16) = 9216 waves chip-wide.
// ---------------------------------------------------------------------------
template <int D, bool LRELU, bool PMOUT>
__global__ __launch_bounds__(512) void omdcn_fused(
    const short* __restrict__ omIn,  // (b,hw,64) bf16 pixel-major — om-conv input
    const short* __restrict__ xT,    // (b,hw,64) bf16 pixel-major — sampling input
    const short* __restrict__ Wom,   // shuffled [tile(8)][kk(36)][lane][8]
    const float* __restrict__ obias, // (216)
    const short* __restrict__ Wd,    // shuffled [tile(2)][kk(36)][lane][8]
    const float* __restrict__ bias,  // (64)
    void* __restrict__ outv) {
  __shared__ __align__(16) char smem[36864 + 13824];
  short* Ls = (short*)smem;                 // 36 kk-slots x 512 shorts
  short* om_lds = (short*)(smem + 36864);   // 216 x 32 bf16
  float* red = (float*)smem;                // aliases Ls (barrier-separated)

  const int tx = threadIdx.x, ty = threadIdx.y;
  const int lid = ty * 32 + tx;
  const int lane = lid & 63, w = lid >> 6;  // 8 waves
  const int col = lane & 31, half = lane >> 5;
  const int pb = blockIdx.x, b = blockIdx.y;
  const int pixbase = pb * 32;

  // ---- phase A: om GEMM, wave w -> oc-tile w (tile 7 is zero-padded) ----
  {
    const short* pixb = omIn + (size_t)b * HWP * 64;
    const short* aP = Wom + ((size_t)(w * 36) * 64 + lane) * 8;
    const int pix = pixbase + col;
    const int yp = pix / WW, xp = pix % WW;
    f32x16 acc = {};
#pragma unroll
    for (int p = 0; p < 9; ++p) {
      const int sy = yp + (p / 3 - 1) * D, sx = xp + (p % 3 - 1) * D;
      const bool valid = ((unsigned)sy < (unsigned)HH) && ((unsigned)sx < (unsigned)WW);
      const short* bsrc = pixb + (size_t)(sy * WW + sx) * 64 + half * 8;
#pragma unroll
      for (int q = 0; q < 4; ++q) {
        const int kk = p * 4 + q;
        short8 B = {0, 0, 0, 0, 0, 0, 0, 0};
        if (valid) B = *(const short8*)(bsrc + q * 16);
        short8 A = *(const short8*)(aP + (size_t)kk * 512);
        acc = __builtin_amdgcn_mfma_f32_32x32x16_bf16(A, B, acc, 0, 0, 0);
      }
    }
    // bias + bf16 round (identical rounding to omB path), write [oc][px]
#pragma unroll
    for (int r = 0; r < 16; ++r) {
      const int rrow = (r & 3) + 8 * (r >> 2) + 4 * half;
      const int oc = w * 32 + rrow;
      if (oc < 216) om_lds[oc * 32 + col] = f2bf(acc[r] + obias[oc]);
    }
  }
  __syncthreads();

  // ---- phase B: sampling; ty = taphalf*8 + dg; 4-5 taps per thread ----
  {
    const int dg = ty & 7, th = ty >> 3;
    const int pixS = pixbase + tx;
    const int ypS = pixS / WW, xpS = pixS % WW;
    const short* xb = xT + (size_t)b * HWP * 64 + dg * 8;
    short* Sp = Ls + (size_t)((dg & 1) * 32 + tx) * 8;

    auto sample_k = [&](int k) {
      float dy = bf2f(om_lds[(dg * 18 + 2 * k) * 32 + tx]);
      float dxv = bf2f(om_lds[(dg * 18 + 2 * k + 1) * 32 + tx]);
      float mr = bf2f(om_lds[(144 + dg * 9 + k) * 32 + tx]);
      float m = 1.f / (1.f + __expf(-mr));
      float py = (float)(ypS + (k / 3 - 1) * D) + dy;
      float px_ = (float)(xpS + (k % 3 - 1) * D) + dxv;
      float y0f = floorf(py), x0f = floorf(px_);
      float ly = py - y0f, lx = px_ - x0f;
      int y0 = (int)y0f, x0 = (int)x0f;
      int y1 = y0 + 1, x1 = x0 + 1;
      bool vy0 = (unsigned)y0 < (unsigned)HH, vy1 = (unsigned)y1 < (unsigned)HH;
      bool vx0 = (unsigned)x0 < (unsigned)WW, vx1 = (unsigned)x1 < (unsigned)WW;
      int cy0 = min(max(y0, 0), HH - 1), cy1 = min(max(y1, 0), HH - 1);
      int cx0 = min(max(x0, 0), WW - 1), cx1 = min(max(x1, 0), WW - 1);
      float w00 = (vy0 && vx0) ? (1.f - ly) * (1.f - lx) * m : 0.f;
      float w01 = (vy0 && vx1) ? (1.f - ly) * lx * m : 0.f;
      float w10 = (vy1 && vx0) ? ly * (1.f - lx) * m : 0.f;
      float w11 = (vy1 && vx1) ? ly * lx * m : 0.f;
      short8 s00 = *(const short8*)(xb + (size_t)(cy0 * WW + cx0) * 64);
      short8 s01 = *(const short8*)(xb + (size_t)(cy0 * WW + cx1) * 64);
      short8 s10 = *(const short8*)(xb + (size_t)(cy1 * WW + cx0) * 64);
      short8 s11 = *(const short8*)(xb + (size_t)(cy1 * WW + cx1) * 64);
      short8 pk;
#pragma unroll
      for (int cl = 0; cl < 8; ++cl) {
        float v = w00 * bf2f(s00[cl]) + w01 * bf2f(s01[cl]) +
                  w10 * bf2f(s10[cl]) + w11 * bf2f(s11[cl]);
        pk[cl] = f2bf(v);
      }
      const int slot = k * 4 + (dg >> 1);
      *(short8*)(Sp + (size_t)slot * 512) = pk;
    };

    if (th == 0) {
      sample_k(0); sample_k(1); sample_k(2); sample_k(3); sample_k(4);
    } else {
      sample_k(5); sample_k(6); sample_k(7); sample_k(8);
    }
  }
  __syncthreads();

  // ---- phase C: DCN GEMM, wave = (octile, kh 0..3), 9 kk each ----
  const int octile = w & 1, kh = w >> 1;
  const short* aPd = Wd + ((size_t)(octile * 36) * 64 + lane) * 8;
  const short* bPd = Ls + (size_t)lane * 8;

  f32x16 accd = {};
#pragma unroll
  for (int i = 0; i < 9; ++i) {
    const int kkg = kh * 9 + i;
    short8 A = *(const short8*)(aPd + (size_t)kkg * 512);
    short8 B = *(const short8*)(bPd + (size_t)kkg * 512);
    accd = __builtin_amdgcn_mfma_f32_32x32x16_bf16(A, B, accd, 0, 0, 0);
  }
  __syncthreads();  // all Ls reads done before red aliases it

  if (kh != 0) {
    float* rp = red + (size_t)(((kh - 1) * 2 + octile) * 64 + lane) * 17;
#pragma unroll
    for (int r = 0; r < 16; ++r) rp[r] = accd[r];
  }
  __syncthreads();

  if (kh == 0) {
    const int pix = pixbase + col;
    const float* r0 = red + (size_t)((0 * 2 + octile) * 64 + lane) * 17;
    const float* r1 = red + (size_t)((2 + octile) * 64 + lane) * 17;
    const float* r2 = red + (size_t)((4 + octile) * 64 + lane) * 17;
    if (PMOUT) {
      short* out = (short*)outv;
#pragma unroll
      for (int rg = 0; rg < 4; ++rg) {
        short4a pk;
#pragma unroll
        for (int i = 0; i < 4; ++i) {
          const int r = rg * 4 + i;
          const int oc = octile * 32 + i + 8 * rg + 4 * half;
          float v = accd[r] + r0[r] + r1[r] + r2[r] + bias[oc];
          if (LRELU) v = (v >= 0.f) ? v : 0.1f * v;
          pk[i] = f2bf(v);
        }
        *(short4a*)(out + ((size_t)b * HWP + pix) * 64 + octile * 32 + 8 * rg + 4 * half) = pk;
      }
    } else {
      float* out = (float*)outv;
#pragma unroll
      for (int r = 0; r < 16; ++r) {
        const int oc = octile * 32 + (r & 3) + 8 * (r >> 2) + 4 * half;
        float v = accd[r] + r0[r] + r1[r] + r2[r] + bias[oc];
        if (LRELU) v = (v >= 0.f) ? v : 0.1f * v;
        out[((size_t)b * NFEAT + oc) * HWP + pix] = v;
      }
    }
  }
}

// ---------------------------------------------------------------------------
extern "C" void kernel_launch(void* const* d_in, const int* in_sizes, int n_in,
                              void* d_out, int out_size, void* d_ws, size_t ws_size,
                              hipStream_t stream) {
  const float* nbr = (const float*)d_in[0];
  const float* ref = (const float*)d_in[1];
  auto f = [&](int i) { return (const float*)d_in[i]; };

  short* s0 = (short*)d_ws;
  const size_t PM = (size_t)BATCH * HWP * 64;   // 2,359,296 shorts
  short* omB = s0;                              // (kept for layout; now unused)
  short* refT = omB + 7962624;
  short* pmA = refT + PM;
  short* pmB = pmA + PM;
  short* pmC = pmB + PM;
  short* pmD = pmC + PM;
  short* pmE = pmD + PM;
  short* pmF = pmE + PM;
  short* pmG = pmF + PM;
  short* wbf = pmG + PM;                        // 589,824
  short* wdcn = wbf + 589824;                   // 147,456
  short* wgc = wdcn + 147456;                   // 188,416
  short* nbrT = (short*)d_out;                  // dead before final write

  // ---- weight prep ----
  prep_om<<<(4 * 147456 + 255) / 256, 256, 0, stream>>>(f(6), f(18), f(30), f(38), wbf);
  prep_dcnw<<<(4 * 36864 + 255) / 256, 256, 0, stream>>>(f(8), f(20), f(32), f(40), wdcn);

  static const int gSrc[12] = {2, 4, 10, 12, 14, 16, 22, 24, 26, 28, 34, 36};
  static const int gCat[12] = {1, 0, 1, 1, 0, 1, 1, 1, 0, 1, 1, 0};
  GwArgs ga;
  int gb = 0;
  const short* wg[12];
  for (int t = 0; t < 12; ++t) {
    ga.src[t] = f(gSrc[t]);
    ga.cat[t] = gCat[t];
    ga.base[t] = gb;
    wg[t] = wgc + gb;
    gb += gCat[t] ? 18432 : 10240;
  }
  ga.base[12] = gb;  // 188,416
  prep_gw<<<(gb + 255) / 256, 256, 0, stream>>>(ga, wgc);

  short* wbf_l3 = wbf;
  short* wbf_l2 = wbf + 147456;
  short* wbf_l1 = wbf + 2 * 147456;
  short* wbf_cas = wbf + 3 * 147456;
  short* wd_l3 = wdcn;
  short* wd_l2 = wdcn + 36864;
  short* wd_l1 = wdcn + 2 * 36864;
  short* wd_cas = wdcn + 3 * 36864;

  dim3 gcGrid(288, BATCH), gcBlk(64, 4);
  dim3 oc1Grid(288, BATCH, 3);
  dim3 fGrid(288, BATCH), fBlk(32, 16);
  dim3 trGrid(HWP / 64, BATCH, 2), trBlk(64, 4);

  transpose_bf16<<<trGrid, trBlk, 0, stream>>>(nbr, nbrT, ref, refT);

  // ---- merged oc1 convs (l3->pmA, l2->pmF, l1->pmG) ----
  Oc1Args oa;
  oa.W[0] = wg[0]; oa.bias[0] = f(3);  oa.out[0] = pmA;
  oa.W[1] = wg[2]; oa.bias[1] = f(11); oa.out[1] = pmF;
  oa.W[2] = wg[6]; oa.bias[2] = f(23); oa.out[2] = pmG;
  gconv_oc1x3<<<oc1Grid, gcBlk, 0, stream>>>(nbrT, refT, oa);

  // ---- level 3 (dilation 5) ----
  gconv_mfma<false, true><<<gcGrid, gcBlk, 0, stream>>>(pmA, nullptr, wg[1], f(5), pmB);
  omdcn_fused<5, true, true><<<fGrid, fBlk, 0, stream>>>(
      pmB, nbrT, wbf_l3, f(7), wd_l3, f(9), pmC);
  // pmB = to_l3, pmC = tf_l3

  // ---- level 2 (dilation 3) ----
  gconv_mfma<true, true><<<gcGrid, gcBlk, 0, stream>>>(pmF, pmB, wg[3], f(13), pmD);
  gconv_mfma<false, true><<<gcGrid, gcBlk, 0, stream>>>(pmD, nullptr, wg[4], f(15), pmE);
  omdcn_fused<3, false, true><<<fGrid, fBlk, 0, stream>>>(
      pmE, nbrT, wbf_l2, f(19), wd_l2, f(21), pmD);
  gconv_mfma<true, true><<<gcGrid, gcBlk, 0, stream>>>(pmD, pmC, wg[5], f(17), pmA);
  // pmE = to_l2, pmA = tf_l2

  // ---- level 1 (dilation 1) ----
  gconv_mfma<true, true><<<gcGrid, gcBlk, 0, stream>>>(pmG, pmE, wg[7], f(25), pmB);
  gconv_mfma<false, true><<<gcGrid, gcBlk, 0, stream>>>(pmB, nullptr, wg[8], f(27), pmC);
  omdcn_fused<1, false, true><<<fGrid, fBlk, 0, stream>>>(
      pmC, nbrT, wbf_l1, f(31), wd_l1, f(33), pmD);
  gconv_mfma<true, false><<<gcGrid, gcBlk, 0, stream>>>(pmD, pmA, wg[9], f(29), pmB);
  // pmB = feat (no lrelu); nbrT (in d_out) now dead

  // ---- cascade (dilation 1) ----
  gconv_mfma<true, true><<<gcGrid, gcBlk, 0, stream>>>(pmB, refT, wg[10], f(35), pmC);
  gconv_mfma<false, true><<<gcGrid, gcBlk, 0, stream>>>(pmC, nullptr, wg[11], f(37), pmD);
  omdcn_fused<1, true, false><<<fGrid, fBlk, 0, stream>>>(
      pmD, pmB, wbf_cas, f(39), wd_cas, f(41), (float*)d_out);
}

// Round 5
// 517.066 us; speedup vs baseline: 1.2607x; 1.2607x over previous
//
#include <hip/hip_runtime.h>

#define BATCH 4
#define NFEAT 64
#define DGRP 8
#define HH 96
#define WW 96
#define HWP (HH*WW)

typedef short short4a __attribute__((ext_vector_type(4)));
typedef short short8 __attribute__((ext_vector_type(8)));
typedef float f32x4 __attribute__((ext_vector_type(4)));
typedef float f32x16 __attribute__((ext_vector_type(16)));

__device__ inline short f2bf(float f) {
  union { float f; unsigned u; } v; v.f = f;
  unsigned r = v.u + 0x7fff + ((v.u >> 16) & 1);
  return (short)(r >> 16);
}
__device__ inline float bf2f(short s) {
  return __uint_as_float(((unsigned)(unsigned short)s) << 16);
}

// Raw barrier that does NOT drain vmcnt (T14 prerequisite): waits only LDS
// ops, leaves global loads in flight across the barrier.
__device__ __forceinline__ void barrier_keep_vmcnt() {
  asm volatile("s_waitcnt lgkmcnt(0)" ::: "memory");
  __builtin_amdgcn_s_barrier();
  asm volatile("" ::: "memory");
}

// ---------------------------------------------------------------------------
// om-weight prep, 32x32 MFMA-A-fragment-shuffled (proven R6).
// ---------------------------------------------------------------------------
__global__ __launch_bounds__(256) void prep_om(
    const float* __restrict__ s0, const float* __restrict__ s1,
    const float* __restrict__ s2, const float* __restrict__ s3,
    short* __restrict__ dst) {
  int gid = blockIdx.x * 256 + threadIdx.x;
  if (gid >= 4 * 147456) return;
  int t = gid / 147456, r = gid % 147456;
  int tile = r / 18432, r2 = r % 18432;
  int kk = r2 / 512, r3 = r2 % 512;
  int lane = r3 / 8, j = r3 % 8;
  int col = lane & 31, half = lane >> 5;
  int oc = tile * 32 + col;
  int k = kk * 16 + half * 8 + j;
  int p = k >> 6, c = k & 63;
  const float* s = (t == 0) ? s0 : (t == 1) ? s1 : (t == 2) ? s2 : s3;
  float v = (oc < 216) ? s[(size_t)oc * 576 + c * 9 + p] : 0.f;
  dst[gid] = f2bf(v);
}

// ---------------------------------------------------------------------------
// dcn-weight prep, same 32x32 A-shuffle: dst[t][tile(2)][kk(36)][lane][8].
// ---------------------------------------------------------------------------
__global__ __launch_bounds__(256) void prep_dcnw(
    const float* __restrict__ s0, const float* __restrict__ s1,
    const float* __restrict__ s2, const float* __restrict__ s3,
    short* __restrict__ dst) {
  int gid = blockIdx.x * 256 + threadIdx.x;
  if (gid >= 4 * 36864) return;
  int t = gid / 36864, r = gid % 36864;
  int tile = r / 18432, r2 = r % 18432;
  int kk = r2 / 512, r3 = r2 % 512;
  int lane = r3 / 8, j = r3 % 8;
  int col = lane & 31, half = lane >> 5;
  int oc = tile * 32 + col;
  int k = kk * 16 + half * 8 + j;
  int p = k >> 6, c = k & 63;
  const float* s = (t == 0) ? s0 : (t == 1) ? s1 : (t == 2) ? s2 : s3;
  dst[gid] = f2bf(s[(size_t)oc * 576 + c * 9 + p]);
}

// ---------------------------------------------------------------------------
// gconv weight prep (proven R7): 16x16x32 A frags, group-pair block-diagonal.
// ---------------------------------------------------------------------------
struct GwArgs {
  const float* src[12];
  int cat[12];
  int base[13];
};

__global__ __launch_bounds__(256) void prep_gw(GwArgs a, short* __restrict__ dst) {
  int gid = blockIdx.x * 256 + threadIdx.x;
  if (gid >= a.base[12]) return;
  int t = 0;
  while (gid >= a.base[t + 1]) ++t;
  int r = gid - a.base[t];
  const float* s = a.src[t];
  const int tsz = a.cat[t] ? 4608 : 2560;
  int tile = r / tsz, r2 = r % tsz;
  int kk = r2 / 512, r3 = r2 % 512;
  int lane = r3 >> 3, j = r3 & 7;
  int m = lane & 15, quad = lane >> 4;
  int oc = tile * 16 + m;
  int j32 = quad * 8 + j;
  float val = 0.f;
  if (a.cat[t]) {
    int gsel = j32 >> 4, ssel = (j32 >> 3) & 1, ch8 = j32 & 7;
    if (gsel == (m >> 3)) val = s[oc * 144 + (2 * ch8 + ssel) * 9 + kk];
  } else {
    int tapsel = j32 >> 4, gsel = (j32 >> 3) & 1, ch8 = j32 & 7;
    int p = 2 * kk + tapsel;
    if (p < 9 && gsel == (m >> 3)) val = s[oc * 72 + ch8 * 9 + p];
  }
  dst[gid] = f2bf(val);
}

// ---------------------------------------------------------------------------
// Channel-major fp32 -> pixel-major bf16; z picks (nbr->nbrT, ref->refT).
// ---------------------------------------------------------------------------
__global__ __launch_bounds__(256) void transpose_bf16(
    const float* __restrict__ in0, short* __restrict__ out0,
    const float* __restrict__ in1, short* __restrict__ out1) {
  const float* in = blockIdx.z ? in1 : in0;
  short* out = blockIdx.z ? out1 : out0;
  __shared__ float s[64][65];
  const int p0 = blockIdx.x * 64;
  const int b = blockIdx.y;
  const int tx = threadIdx.x, ty = threadIdx.y;
  for (int c = ty; c < 64; c += 4)
    s[c][tx] = in[((size_t)b * NFEAT + c) * HWP + p0 + tx];
  __syncthreads();
  for (int p = ty; p < 64; p += 4)
    out[((size_t)b * HWP + p0 + p) * NFEAT + tx] = f2bf(s[tx][p]);
}

// ---------------------------------------------------------------------------
// Grouped 3x3 conv on 16x16x32 MFMA — R7 direct-load version (proven best).
// ---------------------------------------------------------------------------
template <bool CAT, bool LRELU>
__device__ __forceinline__ void gconv_body(
    const short* __restrict__ in0, const short* __restrict__ in1,
    const short* __restrict__ Wsh, const float* __restrict__ bias,
    short* __restrict__ out, int pixbase, int b) {
  const int lane = threadIdx.x, t = threadIdx.y;
  const int n = lane & 15, quad = lane >> 4;
  constexpr int NKK = CAT ? 9 : 5;

  short8 A[NKK];
#pragma unroll
  for (int kk = 0; kk < NKK; ++kk)
    A[kk] = *(const short8*)(Wsh + ((size_t)(t * NKK + kk) * 64 + lane) * 8);

  const short* sb;
  if (CAT) {
    sb = ((quad & 1) ? in1 : in0) + (size_t)b * HWP * 64 + (2 * t + (quad >> 1)) * 8;
  } else {
    sb = in0 + (size_t)b * HWP * 64 + (2 * t + (quad & 1)) * 8;
  }

  f32x4 acc[2] = {};
#pragma unroll
  for (int nt = 0; nt < 2; ++nt) {
    const int pix = pixbase + nt * 16 + n;
    const int yp = pix / WW, xp = pix % WW;
#pragma unroll
    for (int kk = 0; kk < NKK; ++kk) {
      const int p = CAT ? kk : (2 * kk + (quad >> 1));
      short8 B = {0, 0, 0, 0, 0, 0, 0, 0};
      if (p < 9) {
        const int sy = yp + p / 3 - 1, sx = xp + p % 3 - 1;
        if (((unsigned)sy < (unsigned)HH) && ((unsigned)sx < (unsigned)WW))
          B = *(const short8*)(sb + (size_t)(sy * WW + sx) * 64);
      }
      acc[nt] = __builtin_amdgcn_mfma_f32_16x16x32_bf16(A[kk], B, acc[nt], 0, 0, 0);
    }
  }

  const int ocb = t * 16 + quad * 4;
  const float b0 = bias[ocb], b1 = bias[ocb + 1], b2 = bias[ocb + 2], b3 = bias[ocb + 3];
#pragma unroll
  for (int nt = 0; nt < 2; ++nt) {
    float v0 = acc[nt][0] + b0, v1 = acc[nt][1] + b1;
    float v2 = acc[nt][2] + b2, v3 = acc[nt][3] + b3;
    if (LRELU) {
      v0 = (v0 >= 0.f) ? v0 : 0.1f * v0;
      v1 = (v1 >= 0.f) ? v1 : 0.1f * v1;
      v2 = (v2 >= 0.f) ? v2 : 0.1f * v2;
      v3 = (v3 >= 0.f) ? v3 : 0.1f * v3;
    }
    short4a pk = {f2bf(v0), f2bf(v1), f2bf(v2), f2bf(v3)};
    *(short4a*)(out + ((size_t)b * HWP + pixbase + nt * 16 + n) * 64 + ocb) = pk;
  }
}

template <bool CAT, bool LRELU>
__global__ __launch_bounds__(256) void gconv_mfma(
    const short* __restrict__ in0, const short* __restrict__ in1,
    const short* __restrict__ Wsh, const float* __restrict__ bias,
    short* __restrict__ out) {
  gconv_body<CAT, LRELU>(in0, in1, Wsh, bias, out, blockIdx.x * 32, blockIdx.y);
}

// Merged dispatch for the 3 independent oc1 convs (all CAT+LRELU).
struct Oc1Args {
  const short* W[3];
  const float* bias[3];
  short* out[3];
};

__global__ __launch_bounds__(256) void gconv_oc1x3(
    const short* __restrict__ in0, const short* __restrict__ in1, Oc1Args a) {
  const int job = blockIdx.z;
  gconv_body<true, true>(in0, in1, a.W[job], a.bias[job], a.out[job],
                         blockIdx.x * 32, blockIdx.y);
}

// Merged dispatch for 2 independent CAT gconvs (l2-fc || l1-oc2).
struct Pair2Args {
  const short* in0[2];
  const short* in1[2];
  const short* W[2];
  const float* bias[2];
  short* out[2];
};

__global__ __launch_bounds__(256) void gconv_pair(Pair2Args a) {
  const int j = blockIdx.z;
  gconv_body<true, true>(a.in0[j], a.in1[j], a.W[j], a.bias[j], a.out[j],
                         blockIdx.x * 32, blockIdx.y);
}

// ---------------------------------------------------------------------------
// Offset/mask conv (R8 structure + R12 T14 async-stage):
// 64-px blocks, 2x2 register blocking, bf16 out.  Phase-1 tap loads are
// ISSUED into registers before the phase-0 MFMA cluster and ds_written after
// it (async-STAGE split, G15).  Raw barriers keep vmcnt in flight — plain
// __syncthreads would drain vmcnt(0) and serialize the loads (m97 stall).
// Grid (144, BATCH), block (64,4).
// ---------------------------------------------------------------------------
#define BPITCH 324
template <int D>
__global__ __launch_bounds__(256) void omconv_mfma(
    const short* __restrict__ pixT,  // (b, hw, 64) bf16
    const short* __restrict__ Wsh,   // shuffled [tile(8)][kk(36)][lane][8]
    const float* __restrict__ bias,  // (216)
    short* __restrict__ out) {       // (b, 216, hw) bf16
  const int lane = threadIdx.x;
  const int w = threadIdx.y;
  const int lid = w * 64 + lane;
  const int col = lane & 31, half = lane >> 5;
  const int pixbase = blockIdx.x * 64;
  const int b = blockIdx.y;

  __shared__ short Bs[64 * BPITCH];

  const short* aP0 = Wsh + ((size_t)(w * 36) * 64) * 8 + (size_t)lane * 8;
  const short* aP1 = Wsh + ((size_t)((w + 4) * 36) * 64) * 8 + (size_t)lane * 8;
  const short* pixb = pixT + (size_t)b * HWP * 64;

  f32x16 acc00 = {}, acc01 = {}, acc10 = {}, acc11 = {};

  // ---- stage phase-0 taps (p 0..4) into Bs ----
  for (int i = lid; i < 64 * 5 * 8; i += 256) {
    int row = i / 40, q = i % 40;
    int p = q >> 3, c8 = q & 7;
    int pix = pixbase + row;
    int yp = pix / WW, xp = pix % WW;
    int sy = yp + (p / 3 - 1) * D, sx = xp + (p % 3 - 1) * D;
    short4a lo = {0, 0, 0, 0}, hi = {0, 0, 0, 0};
    if (((unsigned)sy < (unsigned)HH) && ((unsigned)sx < (unsigned)WW)) {
      const short* src = pixb + (size_t)(sy * WW + sx) * 64 + c8 * 8;
      lo = *(const short4a*)src;
      hi = *(const short4a*)(src + 4);
    }
    short* dst = Bs + row * BPITCH + q * 8;
    *(short4a*)dst = lo;
    *(short4a*)(dst + 4) = hi;
  }

  // ---- T14: issue phase-1 tap loads (p 5..8) early, keep in regs ----
  short4a p1lo[8], p1hi[8];
  int p1dst[8];
#pragma unroll
  for (int idx = 0; idx < 8; ++idx) {
    int i = lid + idx * 256;               // covers 0..2047 = 64*4*8
    int row = i / 32, q = i % 32;
    int p = 5 + (q >> 3), c8 = q & 7;
    int pix = pixbase + row;
    int yp = pix / WW, xp = pix % WW;
    int sy = yp + (p / 3 - 1) * D, sx = xp + (p % 3 - 1) * D;
    short4a lo = {0, 0, 0, 0}, hi = {0, 0, 0, 0};
    if (((unsigned)sy < (unsigned)HH) && ((unsigned)sx < (unsigned)WW)) {
      const short* src = pixb + (size_t)(sy * WW + sx) * 64 + c8 * 8;
      lo = *(const short4a*)src;
      hi = *(const short4a*)(src + 4);
    }
    p1lo[idx] = lo;
    p1hi[idx] = hi;
    p1dst[idx] = row * BPITCH + q * 8;
  }
  barrier_keep_vmcnt();   // stage-0 LDS visible; phase-1 loads stay in flight

  // ---- MFMA phase 0: kk 0..19 (hides phase-1 load latency) ----
#pragma unroll 4
  for (int kk = 0; kk < 20; ++kk) {
    short8 A0 = *(const short8*)(aP0 + (size_t)kk * 512);
    short8 A1 = *(const short8*)(aP1 + (size_t)kk * 512);
    const short* b0 = Bs + col * BPITCH + kk * 16 + half * 8;
    const short* b1 = Bs + (32 + col) * BPITCH + kk * 16 + half * 8;
    short4a l0 = *(const short4a*)b0, h0 = *(const short4a*)(b0 + 4);
    short4a l1 = *(const short4a*)b1, h1 = *(const short4a*)(b1 + 4);
    short8 B0 = {l0[0], l0[1], l0[2], l0[3], h0[0], h0[1], h0[2], h0[3]};
    short8 B1 = {l1[0], l1[1], l1[2], l1[3], h1[0], h1[1], h1[2], h1[3]};
    acc00 = __builtin_amdgcn_mfma_f32_32x32x16_bf16(A0, B0, acc00, 0, 0, 0);
    acc01 = __builtin_amdgcn_mfma_f32_32x32x16_bf16(A0, B1, acc01, 0, 0, 0);
    acc10 = __builtin_amdgcn_mfma_f32_32x32x16_bf16(A1, B0, acc10, 0, 0, 0);
    acc11 = __builtin_amdgcn_mfma_f32_32x32x16_bf16(A1, B1, acc11, 0, 0, 0);
  }
  barrier_keep_vmcnt();   // all phase-0 Bs reads done before overwrite

  // ---- write phase-1 regs to LDS (compiler waits vmcnt at use) ----
#pragma unroll
  for (int idx = 0; idx < 8; ++idx) {
    short* dst = Bs + p1dst[idx];
    *(short4a*)dst = p1lo[idx];
    *(short4a*)(dst + 4) = p1hi[idx];
  }
  barrier_keep_vmcnt();   // phase-1 LDS visible

  // ---- MFMA phase 1: kk 20..35 (Bs slots 0..15) ----
#pragma unroll 4
  for (int kk = 0; kk < 16; ++kk) {
    const int kkg = 20 + kk;
    short8 A0 = *(const short8*)(aP0 + (size_t)kkg * 512);
    short8 A1 = *(const short8*)(aP1 + (size_t)kkg * 512);
    const short* b0 = Bs + col * BPITCH + kk * 16 + half * 8;
    const short* b1 = Bs + (32 + col) * BPITCH + kk * 16 + half * 8;
    short4a l0 = *(const short4a*)b0, h0 = *(const short4a*)(b0 + 4);
    short4a l1 = *(const short4a*)b1, h1 = *(const short4a*)(b1 + 4);
    short8 B0 = {l0[0], l0[1], l0[2], l0[3], h0[0], h0[1], h0[2], h0[3]};
    short8 B1 = {l1[0], l1[1], l1[2], l1[3], h1[0], h1[1], h1[2], h1[3]};
    acc00 = __builtin_amdgcn_mfma_f32_32x32x16_bf16(A0, B0, acc00, 0, 0, 0);
    acc01 = __builtin_amdgcn_mfma_f32_32x32x16_bf16(A0, B1, acc01, 0, 0, 0);
    acc10 = __builtin_amdgcn_mfma_f32_32x32x16_bf16(A1, B0, acc10, 0, 0, 0);
    acc11 = __builtin_amdgcn_mfma_f32_32x32x16_bf16(A1, B1, acc11, 0, 0, 0);
  }

  const int pix0 = pixbase + col, pix1 = pixbase + 32 + col;
#pragma unroll
  for (int r = 0; r < 16; ++r) {
    const int rrow = (r & 3) + 8 * (r >> 2) + 4 * half;
    const int oc0 = w * 32 + rrow;
    const int oc1 = (w + 4) * 32 + rrow;
    const float bs0 = bias[oc0];
    out[((size_t)b * 216 + oc0) * HWP + pix0] = f2bf(acc00[r] + bs0);
    out[((size_t)b * 216 + oc0) * HWP + pix1] = f2bf(acc01[r] + bs0);
    if (oc1 < 216) {
      const float bs1 = bias[oc1];
      out[((size_t)b * 216 + oc1) * HWP + pix0] = f2bf(acc10[r] + bs1);
      out[((size_t)b * 216 + oc1) * HWP + pix1] = f2bf(acc11[r] + bs1);
    }
  }
}

// ---------------------------------------------------------------------------
// Fused DCN (proven R8): sample -> LDS (B-frag order) -> K-split GEMM.
// ---------------------------------------------------------------------------
template <int D, bool LRELU, bool PMOUT>
__global__ __launch_bounds__(256) void dcn_fused(
    const short* __restrict__ xT,   // (b, hw, 64) bf16 pixel-major
    const short* __restrict__ om,   // (b, 216, hw) bf16
    const short* __restrict__ Wd,   // shuffled [tile(2)][kk(36)][lane][8]
    const float* __restrict__ bias, // (64)
    void* __restrict__ outv) {
  __shared__ short Ls[36 * 512];
  __shared__ float red[2][64][17];
  const int tx = threadIdx.x, ty = threadIdx.y;
  const int pb = blockIdx.x, b = blockIdx.y;

  {
    const int px = tx, dg = ty;
    const int pix = pb * 32 + px;
    const int yp = pix / WW, xp = pix % WW;
    const size_t bOM = (size_t)b * 216 * HWP;
    const short* xb = xT + (size_t)b * HWP * 64 + dg * 8;
    short* Sp = Ls + (size_t)((dg & 1) * 32 + px) * 8;

#pragma unroll
    for (int k = 0; k < 9; ++k) {
      float dy = bf2f(om[bOM + (size_t)(dg * 18 + 2 * k) * HWP + pix]);
      float dxv = bf2f(om[bOM + (size_t)(dg * 18 + 2 * k + 1) * HWP + pix]);
      float mr = bf2f(om[bOM + (size_t)(144 + dg * 9 + k) * HWP + pix]);
      float m = 1.f / (1.f + __expf(-mr));
      float py = (float)(yp + (k / 3 - 1) * D) + dy;
      float px_ = (float)(xp + (k % 3 - 1) * D) + dxv;
      float y0f = floorf(py), x0f = floorf(px_);
      float ly = py - y0f, lx = px_ - x0f;
      int y0 = (int)y0f, x0 = (int)x0f;
      int y1 = y0 + 1, x1 = x0 + 1;
      bool vy0 = (unsigned)y0 < (unsigned)HH, vy1 = (unsigned)y1 < (unsigned)HH;
      bool vx0 = (unsigned)x0 < (unsigned)WW, vx1 = (unsigned)x1 < (unsigned)WW;
      int cy0 = min(max(y0, 0), HH - 1), cy1 = min(max(y1, 0), HH - 1);
      int cx0 = min(max(x0, 0), WW - 1), cx1 = min(max(x1, 0), WW - 1);
      float w00 = (vy0 && vx0) ? (1.f - ly) * (1.f - lx) * m : 0.f;
      float w01 = (vy0 && vx1) ? (1.f - ly) * lx * m : 0.f;
      float w10 = (vy1 && vx0) ? ly * (1.f - lx) * m : 0.f;
      float w11 = (vy1 && vx1) ? ly * lx * m : 0.f;
      short8 s00 = *(const short8*)(xb + (size_t)(cy0 * WW + cx0) * 64);
      short8 s01 = *(const short8*)(xb + (size_t)(cy0 * WW + cx1) * 64);
      short8 s10 = *(const short8*)(xb + (size_t)(cy1 * WW + cx0) * 64);
      short8 s11 = *(const short8*)(xb + (size_t)(cy1 * WW + cx1) * 64);
      short8 pk;
#pragma unroll
      for (int cl = 0; cl < 8; ++cl) {
        float v = w00 * bf2f(s00[cl]) + w01 * bf2f(s01[cl]) +
                  w10 * bf2f(s10[cl]) + w11 * bf2f(s11[cl]);
        pk[cl] = f2bf(v);
      }
      const int kk = k * 4 + (dg >> 1);
      *(short8*)(Sp + (size_t)kk * 512) = pk;
    }
  }
  __syncthreads();

  const int lid = ty * 32 + tx;
  const int lane = lid & 63, w = lid >> 6;
  const int col = lane & 31, half = lane >> 5;
  const int octile = w & 1, kh = w >> 1;
  const int pix = pb * 32 + col;

  const short* aP = Wd + ((size_t)(octile * 36) * 64 + lane) * 8;
  const short* bP = Ls + (size_t)lane * 8;

  f32x16 acc = {};
#pragma unroll 6
  for (int kk = 0; kk < 18; ++kk) {
    const int kkg = kh * 18 + kk;
    short8 A = *(const short8*)(aP + (size_t)kkg * 512);
    short8 B = *(const short8*)(bP + (size_t)kkg * 512);
    acc = __builtin_amdgcn_mfma_f32_32x32x16_bf16(A, B, acc, 0, 0, 0);
  }

  if (kh == 1) {
#pragma unroll
    for (int r = 0; r < 16; ++r) red[octile][lane][r] = acc[r];
  }
  __syncthreads();
  if (kh == 0) {
    if (PMOUT) {
      short* out = (short*)outv;
#pragma unroll
      for (int rg = 0; rg < 4; ++rg) {
        short4a pk;
#pragma unroll
        for (int i = 0; i < 4; ++i) {
          const int r = rg * 4 + i;
          const int oc = octile * 32 + i + 8 * rg + 4 * half;
          float v = acc[r] + red[octile][lane][r] + bias[oc];
          if (LRELU) v = (v >= 0.f) ? v : 0.1f * v;
          pk[i] = f2bf(v);
        }
        *(short4a*)(out + ((size_t)b * HWP + pix) * 64 + octile * 32 + 8 * rg + 4 * half) = pk;
      }
    } else {
      float* out = (float*)outv;
#pragma unroll
      for (int r = 0; r < 16; ++r) {
        const int oc = octile * 32 + (r & 3) + 8 * (r >> 2) + 4 * half;
        float v = acc[r] + red[octile][lane][r] + bias[oc];
        if (LRELU) v = (v >= 0.f) ? v : 0.1f * v;
        out[((size_t)b * NFEAT + oc) * HWP + pix] = v;
      }
    }
  }
}

// ---------------------------------------------------------------------------
extern "C" void kernel_launch(void* const* d_in, const int* in_sizes, int n_in,
                              void* d_out, int out_size, void* d_ws, size_t ws_size,
                              hipStream_t stream) {
  const float* nbr = (const float*)d_in[0];
  const float* ref = (const float*)d_in[1];
  auto f = [&](int i) { return (const float*)d_in[i]; };

  short* s0 = (short*)d_ws;
  const size_t PM = (size_t)BATCH * HWP * 64;   // 2,359,296 shorts
  short* omB = s0;                              // 7,962,624 shorts
  short* refT = omB + 7962624;
  short* pmA = refT + PM;
  short* pmB = pmA + PM;
  short* pmC = pmB + PM;
  short* pmD = pmC + PM;
  short* pmE = pmD + PM;
  short* pmF = pmE + PM;
  short* pmG = pmF + PM;
  short* wbf = pmG + PM;                        // 589,824
  short* wdcn = wbf + 589824;                   // 147,456
  short* wgc = wdcn + 147456;                   // 188,416
  short* nbrT = (short*)d_out;                  // dead before final write

  // ---- weight prep ----
  prep_om<<<(4 * 147456 + 255) / 256, 256, 0, stream>>>(f(6), f(18), f(30), f(38), wbf);
  prep_dcnw<<<(4 * 36864 + 255) / 256, 256, 0, stream>>>(f(8), f(20), f(32), f(40), wdcn);

  static const int gSrc[12] = {2, 4, 10, 12, 14, 16, 22, 24, 26, 28, 34, 36};
  static const int gCat[12] = {1, 0, 1, 1, 0, 1, 1, 1, 0, 1, 1, 0};
  GwArgs ga;
  int gb = 0;
  const short* wg[12];
  for (int t = 0; t < 12; ++t) {
    ga.src[t] = f(gSrc[t]);
    ga.cat[t] = gCat[t];
    ga.base[t] = gb;
    wg[t] = wgc + gb;
    gb += gCat[t] ? 18432 : 10240;
  }
  ga.base[12] = gb;  // 188,416
  prep_gw<<<(gb + 255) / 256, 256, 0, stream>>>(ga, wgc);

  short* wbf_l3 = wbf;
  short* wbf_l2 = wbf + 147456;
  short* wbf_l1 = wbf + 2 * 147456;
  short* wbf_cas = wbf + 3 * 147456;
  short* wd_l3 = wdcn;
  short* wd_l2 = wdcn + 36864;
  short* wd_l1 = wdcn + 2 * 36864;
  short* wd_cas = wdcn + 3 * 36864;

  dim3 gcGrid(288, BATCH), gcBlk(64, 4);
  dim3 oc1Grid(288, BATCH, 3);
  dim3 pairGrid(288, BATCH, 2);
  dim3 omGrid(144, BATCH), omBlk(64, 4);
  dim3 dfGrid(288, BATCH), dfBlk(32, 8);
  dim3 trGrid(HWP / 64, BATCH, 2), trBlk(64, 4);

  transpose_bf16<<<trGrid, trBlk, 0, stream>>>(nbr, nbrT, ref, refT);

  // ---- merged oc1 convs (l3->pmA, l2->pmF, l1->pmG) ----
  Oc1Args oa;
  oa.W[0] = wg[0]; oa.bias[0] = f(3);  oa.out[0] = pmA;
  oa.W[1] = wg[2]; oa.bias[1] = f(11); oa.out[1] = pmF;
  oa.W[2] = wg[6]; oa.bias[2] = f(23); oa.out[2] = pmG;
  gconv_oc1x3<<<oc1Grid, gcBlk, 0, stream>>>(nbrT, refT, oa);

  // ---- level 3 (dilation 5) ----
  gconv_mfma<false, true><<<gcGrid, gcBlk, 0, stream>>>(pmA, nullptr, wg[1], f(5), pmB);
  omconv_mfma<5><<<omGrid, omBlk, 0, stream>>>(pmB, wbf_l3, f(7), omB);
  dcn_fused<5, true, true><<<dfGrid, dfBlk, 0, stream>>>(nbrT, omB, wd_l3, f(9), pmC);
  // pmB = to_l3, pmC = tf_l3

  // ---- level 2 (dilation 3) ----
  gconv_mfma<true, true><<<gcGrid, gcBlk, 0, stream>>>(pmF, pmB, wg[3], f(13), pmD);
  gconv_mfma<false, true><<<gcGrid, gcBlk, 0, stream>>>(pmD, nullptr, wg[4], f(15), pmE);
  omconv_mfma<3><<<omGrid, omBlk, 0, stream>>>(pmE, wbf_l2, f(19), omB);
  dcn_fused<3, false, true><<<dfGrid, dfBlk, 0, stream>>>(nbrT, omB, wd_l2, f(21), pmD);
  // pmE = to_l2

  // ---- merged {l2-fc, l1-oc2} (independent: pmD,pmC -> pmA || pmG,pmE -> pmB)
  Pair2Args pa;
  pa.in0[0] = pmD; pa.in1[0] = pmC; pa.W[0] = wg[5]; pa.bias[0] = f(17); pa.out[0] = pmA;
  pa.in0[1] = pmG; pa.in1[1] = pmE; pa.W[1] = wg[7]; pa.bias[1] = f(25); pa.out[1] = pmB;
  gconv_pair<<<pairGrid, gcBlk, 0, stream>>>(pa);
  // pmA = tf_l2, pmB = l1 off1

  // ---- level 1 (dilation 1) ----
  gconv_mfma<false, true><<<gcGrid, gcBlk, 0, stream>>>(pmB, nullptr, wg[8], f(27), pmC);
  omconv_mfma<1><<<omGrid, omBlk, 0, stream>>>(pmC, wbf_l1, f(31), omB);
  dcn_fused<1, false, true><<<dfGrid, dfBlk, 0, stream>>>(nbrT, omB, wd_l1, f(33), pmD);
  gconv_mfma<true, false><<<gcGrid, gcBlk, 0, stream>>>(pmD, pmA, wg[9], f(29), pmB);
  // pmB = feat (no lrelu); nbrT (in d_out) now dead

  // ---- cascade (dilation 1) ----
  gconv_mfma<true, true><<<gcGrid, gcBlk, 0, stream>>>(pmB, refT, wg[10], f(35), pmC);
  gconv_mfma<false, true><<<gcGrid, gcBlk, 0, stream>>>(pmC, nullptr, wg[11], f(37), pmD);
  omconv_mfma<1><<<omGrid, omBlk, 0, stream>>>(pmD, wbf_cas, f(39), omB);
  dcn_fused<1, true, false><<<dfGrid, dfBlk, 0, stream>>>(pmB, omB, wd_cas, f(41), (float*)d_out);
}

// Round 6
// 505.256 us; speedup vs baseline: 1.2902x; 1.0234x over previous
//
#include <hip/hip_runtime.h>

#define BATCH 4
#define NFEAT 64
#define DGRP 8
#define HH 96
#define WW 96
#define HWP (HH*WW)

typedef short short4a __attribute__((ext_vector_type(4)));
typedef short short8 __attribute__((ext_vector_type(8)));
typedef float f32x4 __attribute__((ext_vector_type(4)));
typedef float f32x16 __attribute__((ext_vector_type(16)));

__device__ inline short f2bf(float f) {
  union { float f; unsigned u; } v; v.f = f;
  unsigned r = v.u + 0x7fff + ((v.u >> 16) & 1);
  return (short)(r >> 16);
}
__device__ inline float bf2f(short s) {
  return __uint_as_float(((unsigned)(unsigned short)s) << 16);
}

// Raw barrier that does NOT drain vmcnt (T14 prerequisite).
__device__ __forceinline__ void barrier_keep_vmcnt() {
  asm volatile("s_waitcnt lgkmcnt(0)" ::: "memory");
  __builtin_amdgcn_s_barrier();
  asm volatile("" ::: "memory");
}

// ---------------------------------------------------------------------------
// om-weight prep, 32x32 MFMA-A-fragment-shuffled (proven R6).
// ---------------------------------------------------------------------------
__global__ __launch_bounds__(256) void prep_om(
    const float* __restrict__ s0, const float* __restrict__ s1,
    const float* __restrict__ s2, const float* __restrict__ s3,
    short* __restrict__ dst) {
  int gid = blockIdx.x * 256 + threadIdx.x;
  if (gid >= 4 * 147456) return;
  int t = gid / 147456, r = gid % 147456;
  int tile = r / 18432, r2 = r % 18432;
  int kk = r2 / 512, r3 = r2 % 512;
  int lane = r3 / 8, j = r3 % 8;
  int col = lane & 31, half = lane >> 5;
  int oc = tile * 32 + col;
  int k = kk * 16 + half * 8 + j;
  int p = k >> 6, c = k & 63;
  const float* s = (t == 0) ? s0 : (t == 1) ? s1 : (t == 2) ? s2 : s3;
  float v = (oc < 216) ? s[(size_t)oc * 576 + c * 9 + p] : 0.f;
  dst[gid] = f2bf(v);
}

// ---------------------------------------------------------------------------
// dcn-weight prep, same 32x32 A-shuffle: dst[t][tile(2)][kk(36)][lane][8].
// ---------------------------------------------------------------------------
__global__ __launch_bounds__(256) void prep_dcnw(
    const float* __restrict__ s0, const float* __restrict__ s1,
    const float* __restrict__ s2, const float* __restrict__ s3,
    short* __restrict__ dst) {
  int gid = blockIdx.x * 256 + threadIdx.x;
  if (gid >= 4 * 36864) return;
  int t = gid / 36864, r = gid % 36864;
  int tile = r / 18432, r2 = r % 18432;
  int kk = r2 / 512, r3 = r2 % 512;
  int lane = r3 / 8, j = r3 % 8;
  int col = lane & 31, half = lane >> 5;
  int oc = tile * 32 + col;
  int k = kk * 16 + half * 8 + j;
  int p = k >> 6, c = k & 63;
  const float* s = (t == 0) ? s0 : (t == 1) ? s1 : (t == 2) ? s2 : s3;
  dst[gid] = f2bf(s[(size_t)oc * 576 + c * 9 + p]);
}

// ---------------------------------------------------------------------------
// gconv weight prep (proven R7): 16x16x32 A frags, group-pair block-diagonal.
// ---------------------------------------------------------------------------
struct GwArgs {
  const float* src[12];
  int cat[12];
  int base[13];
};

__global__ __launch_bounds__(256) void prep_gw(GwArgs a, short* __restrict__ dst) {
  int gid = blockIdx.x * 256 + threadIdx.x;
  if (gid >= a.base[12]) return;
  int t = 0;
  while (gid >= a.base[t + 1]) ++t;
  int r = gid - a.base[t];
  const float* s = a.src[t];
  const int tsz = a.cat[t] ? 4608 : 2560;
  int tile = r / tsz, r2 = r % tsz;
  int kk = r2 / 512, r3 = r2 % 512;
  int lane = r3 >> 3, j = r3 & 7;
  int m = lane & 15, quad = lane >> 4;
  int oc = tile * 16 + m;
  int j32 = quad * 8 + j;
  float val = 0.f;
  if (a.cat[t]) {
    int gsel = j32 >> 4, ssel = (j32 >> 3) & 1, ch8 = j32 & 7;
    if (gsel == (m >> 3)) val = s[oc * 144 + (2 * ch8 + ssel) * 9 + kk];
  } else {
    int tapsel = j32 >> 4, gsel = (j32 >> 3) & 1, ch8 = j32 & 7;
    int p = 2 * kk + tapsel;
    if (p < 9 && gsel == (m >> 3)) val = s[oc * 72 + ch8 * 9 + p];
  }
  dst[gid] = f2bf(val);
}

// ---------------------------------------------------------------------------
// Channel-major fp32 -> pixel-major bf16; z picks (nbr->nbrT, ref->refT).
// ---------------------------------------------------------------------------
__global__ __launch_bounds__(256) void transpose_bf16(
    const float* __restrict__ in0, short* __restrict__ out0,
    const float* __restrict__ in1, short* __restrict__ out1) {
  const float* in = blockIdx.z ? in1 : in0;
  short* out = blockIdx.z ? out1 : out0;
  __shared__ float s[64][65];
  const int p0 = blockIdx.x * 64;
  const int b = blockIdx.y;
  const int tx = threadIdx.x, ty = threadIdx.y;
  for (int c = ty; c < 64; c += 4)
    s[c][tx] = in[((size_t)b * NFEAT + c) * HWP + p0 + tx];
  __syncthreads();
  for (int p = ty; p < 64; p += 4)
    out[((size_t)b * HWP + p0 + p) * NFEAT + tx] = f2bf(s[tx][p]);
}

// ---------------------------------------------------------------------------
// Grouped 3x3 conv body (proven R7 direct-load).  Flat-256 lid:
// lane = lid&63, t = lid>>6 — identical mapping to old (64,4) block.
// ---------------------------------------------------------------------------
template <bool CAT, bool LRELU>
__device__ __forceinline__ void gconv_body(
    const short* __restrict__ in0, const short* __restrict__ in1,
    const short* __restrict__ Wsh, const float* __restrict__ bias,
    short* __restrict__ out, int pixbase, int b, int lid) {
  const int lane = lid & 63, t = lid >> 6;
  const int n = lane & 15, quad = lane >> 4;
  constexpr int NKK = CAT ? 9 : 5;

  short8 A[NKK];
#pragma unroll
  for (int kk = 0; kk < NKK; ++kk)
    A[kk] = *(const short8*)(Wsh + ((size_t)(t * NKK + kk) * 64 + lane) * 8);

  const short* sb;
  if (CAT) {
    sb = ((quad & 1) ? in1 : in0) + (size_t)b * HWP * 64 + (2 * t + (quad >> 1)) * 8;
  } else {
    sb = in0 + (size_t)b * HWP * 64 + (2 * t + (quad & 1)) * 8;
  }

  f32x4 acc[2] = {};
#pragma unroll
  for (int nt = 0; nt < 2; ++nt) {
    const int pix = pixbase + nt * 16 + n;
    const int yp = pix / WW, xp = pix % WW;
#pragma unroll
    for (int kk = 0; kk < NKK; ++kk) {
      const int p = CAT ? kk : (2 * kk + (quad >> 1));
      short8 B = {0, 0, 0, 0, 0, 0, 0, 0};
      if (p < 9) {
        const int sy = yp + p / 3 - 1, sx = xp + p % 3 - 1;
        if (((unsigned)sy < (unsigned)HH) && ((unsigned)sx < (unsigned)WW))
          B = *(const short8*)(sb + (size_t)(sy * WW + sx) * 64);
      }
      acc[nt] = __builtin_amdgcn_mfma_f32_16x16x32_bf16(A[kk], B, acc[nt], 0, 0, 0);
    }
  }

  const int ocb = t * 16 + quad * 4;
  const float b0 = bias[ocb], b1 = bias[ocb + 1], b2 = bias[ocb + 2], b3 = bias[ocb + 3];
#pragma unroll
  for (int nt = 0; nt < 2; ++nt) {
    float v0 = acc[nt][0] + b0, v1 = acc[nt][1] + b1;
    float v2 = acc[nt][2] + b2, v3 = acc[nt][3] + b3;
    if (LRELU) {
      v0 = (v0 >= 0.f) ? v0 : 0.1f * v0;
      v1 = (v1 >= 0.f) ? v1 : 0.1f * v1;
      v2 = (v2 >= 0.f) ? v2 : 0.1f * v2;
      v3 = (v3 >= 0.f) ? v3 : 0.1f * v3;
    }
    short4a pk = {f2bf(v0), f2bf(v1), f2bf(v2), f2bf(v3)};
    *(short4a*)(out + ((size_t)b * HWP + pixbase + nt * 16 + n) * 64 + ocb) = pk;
  }
}

template <bool CAT, bool LRELU>
__global__ __launch_bounds__(256) void gconv_mfma(
    const short* __restrict__ in0, const short* __restrict__ in1,
    const short* __restrict__ Wsh, const float* __restrict__ bias,
    short* __restrict__ out) {
  gconv_body<CAT, LRELU>(in0, in1, Wsh, bias, out, blockIdx.x * 32, blockIdx.y,
                         threadIdx.x);
}

// Merged dispatch for the 3 independent oc1 convs (all CAT+LRELU).
struct Oc1Args {
  const short* W[3];
  const float* bias[3];
  short* out[3];
};

__global__ __launch_bounds__(256) void gconv_oc1x3(
    const short* __restrict__ in0, const short* __restrict__ in1, Oc1Args a) {
  const int job = blockIdx.z;
  gconv_body<true, true>(in0, in1, a.W[job], a.bias[job], a.out[job],
                         blockIdx.x * 32, blockIdx.y, threadIdx.x);
}

// ---------------------------------------------------------------------------
// Offset/mask conv body (R8 + T14 async-stage, proven R12/517us).
// Flat lid: lane = lid&63, w = lid>>6.  Bs passed in (41,472 B).
// ---------------------------------------------------------------------------
#define BPITCH 324
template <int D>
__device__ __forceinline__ void omconv_body(
    short* Bs,
    const short* __restrict__ pixT, const short* __restrict__ Wsh,
    const float* __restrict__ bias, short* __restrict__ out,
    int xblk, int b, int lid) {
  const int lane = lid & 63;
  const int w = lid >> 6;
  const int col = lane & 31, half = lane >> 5;
  const int pixbase = xblk * 64;

  const short* aP0 = Wsh + ((size_t)(w * 36) * 64) * 8 + (size_t)lane * 8;
  const short* aP1 = Wsh + ((size_t)((w + 4) * 36) * 64) * 8 + (size_t)lane * 8;
  const short* pixb = pixT + (size_t)b * HWP * 64;

  f32x16 acc00 = {}, acc01 = {}, acc10 = {}, acc11 = {};

  // ---- stage phase-0 taps (p 0..4) into Bs ----
  for (int i = lid; i < 64 * 5 * 8; i += 256) {
    int row = i / 40, q = i % 40;
    int p = q >> 3, c8 = q & 7;
    int pix = pixbase + row;
    int yp = pix / WW, xp = pix % WW;
    int sy = yp + (p / 3 - 1) * D, sx = xp + (p % 3 - 1) * D;
    short4a lo = {0, 0, 0, 0}, hi = {0, 0, 0, 0};
    if (((unsigned)sy < (unsigned)HH) && ((unsigned)sx < (unsigned)WW)) {
      const short* src = pixb + (size_t)(sy * WW + sx) * 64 + c8 * 8;
      lo = *(const short4a*)src;
      hi = *(const short4a*)(src + 4);
    }
    short* dst = Bs + row * BPITCH + q * 8;
    *(short4a*)dst = lo;
    *(short4a*)(dst + 4) = hi;
  }

  // ---- T14: issue phase-1 tap loads (p 5..8) early, keep in regs ----
  short4a p1lo[8], p1hi[8];
  int p1dst[8];
#pragma unroll
  for (int idx = 0; idx < 8; ++idx) {
    int i = lid + idx * 256;               // covers 0..2047 = 64*4*8
    int row = i / 32, q = i % 32;
    int p = 5 + (q >> 3), c8 = q & 7;
    int pix = pixbase + row;
    int yp = pix / WW, xp = pix % WW;
    int sy = yp + (p / 3 - 1) * D, sx = xp + (p % 3 - 1) * D;
    short4a lo = {0, 0, 0, 0}, hi = {0, 0, 0, 0};
    if (((unsigned)sy < (unsigned)HH) && ((unsigned)sx < (unsigned)WW)) {
      const short* src = pixb + (size_t)(sy * WW + sx) * 64 + c8 * 8;
      lo = *(const short4a*)src;
      hi = *(const short4a*)(src + 4);
    }
    p1lo[idx] = lo;
    p1hi[idx] = hi;
    p1dst[idx] = row * BPITCH + q * 8;
  }
  barrier_keep_vmcnt();   // stage-0 LDS visible; phase-1 loads stay in flight

  // ---- MFMA phase 0: kk 0..19 (hides phase-1 load latency) ----
#pragma unroll 4
  for (int kk = 0; kk < 20; ++kk) {
    short8 A0 = *(const short8*)(aP0 + (size_t)kk * 512);
    short8 A1 = *(const short8*)(aP1 + (size_t)kk * 512);
    const short* b0 = Bs + col * BPITCH + kk * 16 + half * 8;
    const short* b1 = Bs + (32 + col) * BPITCH + kk * 16 + half * 8;
    short4a l0 = *(const short4a*)b0, h0 = *(const short4a*)(b0 + 4);
    short4a l1 = *(const short4a*)b1, h1 = *(const short4a*)(b1 + 4);
    short8 B0 = {l0[0], l0[1], l0[2], l0[3], h0[0], h0[1], h0[2], h0[3]};
    short8 B1 = {l1[0], l1[1], l1[2], l1[3], h1[0], h1[1], h1[2], h1[3]};
    acc00 = __builtin_amdgcn_mfma_f32_32x32x16_bf16(A0, B0, acc00, 0, 0, 0);
    acc01 = __builtin_amdgcn_mfma_f32_32x32x16_bf16(A0, B1, acc01, 0, 0, 0);
    acc10 = __builtin_amdgcn_mfma_f32_32x32x16_bf16(A1, B0, acc10, 0, 0, 0);
    acc11 = __builtin_amdgcn_mfma_f32_32x32x16_bf16(A1, B1, acc11, 0, 0, 0);
  }
  barrier_keep_vmcnt();   // all phase-0 Bs reads done before overwrite

  // ---- write phase-1 regs to LDS (compiler waits vmcnt at use) ----
#pragma unroll
  for (int idx = 0; idx < 8; ++idx) {
    short* dst = Bs + p1dst[idx];
    *(short4a*)dst = p1lo[idx];
    *(short4a*)(dst + 4) = p1hi[idx];
  }
  barrier_keep_vmcnt();   // phase-1 LDS visible

  // ---- MFMA phase 1: kk 20..35 (Bs slots 0..15) ----
#pragma unroll 4
  for (int kk = 0; kk < 16; ++kk) {
    const int kkg = 20 + kk;
    short8 A0 = *(const short8*)(aP0 + (size_t)kkg * 512);
    short8 A1 = *(const short8*)(aP1 + (size_t)kkg * 512);
    const short* b0 = Bs + col * BPITCH + kk * 16 + half * 8;
    const short* b1 = Bs + (32 + col) * BPITCH + kk * 16 + half * 8;
    short4a l0 = *(const short4a*)b0, h0 = *(const short4a*)(b0 + 4);
    short4a l1 = *(const short4a*)b1, h1 = *(const short4a*)(b1 + 4);
    short8 B0 = {l0[0], l0[1], l0[2], l0[3], h0[0], h0[1], h0[2], h0[3]};
    short8 B1 = {l1[0], l1[1], l1[2], l1[3], h1[0], h1[1], h1[2], h1[3]};
    acc00 = __builtin_amdgcn_mfma_f32_32x32x16_bf16(A0, B0, acc00, 0, 0, 0);
    acc01 = __builtin_amdgcn_mfma_f32_32x32x16_bf16(A0, B1, acc01, 0, 0, 0);
    acc10 = __builtin_amdgcn_mfma_f32_32x32x16_bf16(A1, B0, acc10, 0, 0, 0);
    acc11 = __builtin_amdgcn_mfma_f32_32x32x16_bf16(A1, B1, acc11, 0, 0, 0);
  }

  const int pix0 = pixbase + col, pix1 = pixbase + 32 + col;
#pragma unroll
  for (int r = 0; r < 16; ++r) {
    const int rrow = (r & 3) + 8 * (r >> 2) + 4 * half;
    const int oc0 = w * 32 + rrow;
    const int oc1 = (w + 4) * 32 + rrow;
    const float bs0 = bias[oc0];
    out[((size_t)b * 216 + oc0) * HWP + pix0] = f2bf(acc00[r] + bs0);
    out[((size_t)b * 216 + oc0) * HWP + pix1] = f2bf(acc01[r] + bs0);
    if (oc1 < 216) {
      const float bs1 = bias[oc1];
      out[((size_t)b * 216 + oc1) * HWP + pix0] = f2bf(acc10[r] + bs1);
      out[((size_t)b * 216 + oc1) * HWP + pix1] = f2bf(acc11[r] + bs1);
    }
  }
}

template <int D>
__global__ __launch_bounds__(256) void omconv_mfma(
    const short* __restrict__ pixT, const short* __restrict__ Wsh,
    const float* __restrict__ bias, short* __restrict__ out) {
  __shared__ short Bs[64 * BPITCH];
  omconv_body<D>(Bs, pixT, Wsh, bias, out, blockIdx.x, blockIdx.y, threadIdx.x);
}

// ---------------------------------------------------------------------------
// Fused DCN body (proven R8): sample -> LDS (B-frag order) -> K-split GEMM.
// Flat lid: tx = lid&31, ty = lid>>5.  smem = Ls(36864) + red(8704) = 45568.
// ---------------------------------------------------------------------------
template <int D, bool LRELU, bool PMOUT>
__device__ __forceinline__ void dcn_body(
    char* smem,
    const short* __restrict__ xT, const short* __restrict__ om,
    const short* __restrict__ Wd, const float* __restrict__ bias,
    void* __restrict__ outv, int pb, int b, int lid) {
  short* Ls = (short*)smem;
  float* red = (float*)(smem + 36864);
  const int tx = lid & 31, ty = lid >> 5;

  {
    const int px = tx, dg = ty;
    const int pix = pb * 32 + px;
    const int yp = pix / WW, xp = pix % WW;
    const size_t bOM = (size_t)b * 216 * HWP;
    const short* xb = xT + (size_t)b * HWP * 64 + dg * 8;
    short* Sp = Ls + (size_t)((dg & 1) * 32 + px) * 8;

#pragma unroll
    for (int k = 0; k < 9; ++k) {
      float dy = bf2f(om[bOM + (size_t)(dg * 18 + 2 * k) * HWP + pix]);
      float dxv = bf2f(om[bOM + (size_t)(dg * 18 + 2 * k + 1) * HWP + pix]);
      float mr = bf2f(om[bOM + (size_t)(144 + dg * 9 + k) * HWP + pix]);
      float m = 1.f / (1.f + __expf(-mr));
      float py = (float)(yp + (k / 3 - 1) * D) + dy;
      float px_ = (float)(xp + (k % 3 - 1) * D) + dxv;
      float y0f = floorf(py), x0f = floorf(px_);
      float ly = py - y0f, lx = px_ - x0f;
      int y0 = (int)y0f, x0 = (int)x0f;
      int y1 = y0 + 1, x1 = x0 + 1;
      bool vy0 = (unsigned)y0 < (unsigned)HH, vy1 = (unsigned)y1 < (unsigned)HH;
      bool vx0 = (unsigned)x0 < (unsigned)WW, vx1 = (unsigned)x1 < (unsigned)WW;
      int cy0 = min(max(y0, 0), HH - 1), cy1 = min(max(y1, 0), HH - 1);
      int cx0 = min(max(x0, 0), WW - 1), cx1 = min(max(x1, 0), WW - 1);
      float w00 = (vy0 && vx0) ? (1.f - ly) * (1.f - lx) * m : 0.f;
      float w01 = (vy0 && vx1) ? (1.f - ly) * lx * m : 0.f;
      float w10 = (vy1 && vx0) ? ly * (1.f - lx) * m : 0.f;
      float w11 = (vy1 && vx1) ? ly * lx * m : 0.f;
      short8 s00 = *(const short8*)(xb + (size_t)(cy0 * WW + cx0) * 64);
      short8 s01 = *(const short8*)(xb + (size_t)(cy0 * WW + cx1) * 64);
      short8 s10 = *(const short8*)(xb + (size_t)(cy1 * WW + cx0) * 64);
      short8 s11 = *(const short8*)(xb + (size_t)(cy1 * WW + cx1) * 64);
      short8 pk;
#pragma unroll
      for (int cl = 0; cl < 8; ++cl) {
        float v = w00 * bf2f(s00[cl]) + w01 * bf2f(s01[cl]) +
                  w10 * bf2f(s10[cl]) + w11 * bf2f(s11[cl]);
        pk[cl] = f2bf(v);
      }
      const int kk = k * 4 + (dg >> 1);
      *(short8*)(Sp + (size_t)kk * 512) = pk;
    }
  }
  __syncthreads();

  const int lane = lid & 63, w = lid >> 6;
  const int col = lane & 31, half = lane >> 5;
  const int octile = w & 1, kh = w >> 1;
  const int pix = pb * 32 + col;

  const short* aP = Wd + ((size_t)(octile * 36) * 64 + lane) * 8;
  const short* bP = Ls + (size_t)lane * 8;

  f32x16 acc = {};
#pragma unroll 6
  for (int kk = 0; kk < 18; ++kk) {
    const int kkg = kh * 18 + kk;
    short8 A = *(const short8*)(aP + (size_t)kkg * 512);
    short8 B = *(const short8*)(bP + (size_t)kkg * 512);
    acc = __builtin_amdgcn_mfma_f32_32x32x16_bf16(A, B, acc, 0, 0, 0);
  }

  if (kh == 1) {
#pragma unroll
    for (int r = 0; r < 16; ++r) red[((size_t)octile * 64 + lane) * 17 + r] = acc[r];
  }
  __syncthreads();
  if (kh == 0) {
    const float* rp = red + ((size_t)octile * 64 + lane) * 17;
    if (PMOUT) {
      short* out = (short*)outv;
#pragma unroll
      for (int rg = 0; rg < 4; ++rg) {
        short4a pk;
#pragma unroll
        for (int i = 0; i < 4; ++i) {
          const int r = rg * 4 + i;
          const int oc = octile * 32 + i + 8 * rg + 4 * half;
          float v = acc[r] + rp[r] + bias[oc];
          if (LRELU) v = (v >= 0.f) ? v : 0.1f * v;
          pk[i] = f2bf(v);
        }
        *(short4a*)(out + ((size_t)b * HWP + pix) * 64 + octile * 32 + 8 * rg + 4 * half) = pk;
      }
    } else {
      float* out = (float*)outv;
#pragma unroll
      for (int r = 0; r < 16; ++r) {
        const int oc = octile * 32 + (r & 3) + 8 * (r >> 2) + 4 * half;
        float v = acc[r] + rp[r] + bias[oc];
        if (LRELU) v = (v >= 0.f) ? v : 0.1f * v;
        out[((size_t)b * NFEAT + oc) * HWP + pix] = v;
      }
    }
  }
}

template <int D, bool LRELU, bool PMOUT>
__global__ __launch_bounds__(256) void dcn_fused(
    const short* __restrict__ xT, const short* __restrict__ om,
    const short* __restrict__ Wd, const float* __restrict__ bias,
    void* __restrict__ outv) {
  __shared__ char smem[45568];
  dcn_body<D, LRELU, PMOUT>(smem, xT, om, Wd, bias, outv,
                            blockIdx.x, blockIdx.y, threadIdx.x);
}

// ---------------------------------------------------------------------------
// Fat dispatches (R13): co-schedule an om-conv / dcn with an INDEPENDENT
// gconv from the next level via blockIdx.x partition.  Latency-bound kernels
// fill each other's stalls (m114: MFMA/VALU waves co-schedule freely).
// ---------------------------------------------------------------------------
template <int D>
__global__ __launch_bounds__(256) void om_gc(
    const short* __restrict__ pixT, const short* __restrict__ Wom,
    const float* __restrict__ obias, short* __restrict__ omOut,
    const short* __restrict__ g0, const short* __restrict__ g1,
    const short* __restrict__ gW, const float* __restrict__ gb,
    short* __restrict__ gout) {
  __shared__ short Bs[64 * BPITCH];
  if (blockIdx.x < 144)
    omconv_body<D>(Bs, pixT, Wom, obias, omOut, blockIdx.x, blockIdx.y, threadIdx.x);
  else
    gconv_body<true, true>(g0, g1, gW, gb, gout, (blockIdx.x - 144) * 32,
                           blockIdx.y, threadIdx.x);
}

template <int D, bool DLRELU>
__global__ __launch_bounds__(256) void dcn_gc(
    const short* __restrict__ xT, const short* __restrict__ om,
    const short* __restrict__ Wd, const float* __restrict__ dbias,
    short* __restrict__ dout,
    const short* __restrict__ g0, const short* __restrict__ gW,
    const float* __restrict__ gb, short* __restrict__ gout) {
  __shared__ char smem[45568];
  if (blockIdx.x < 288)
    dcn_body<D, DLRELU, true>(smem, xT, om, Wd, dbias, dout,
                              blockIdx.x, blockIdx.y, threadIdx.x);
  else
    gconv_body<false, true>(g0, nullptr, gW, gb, gout, (blockIdx.x - 288) * 32,
                            blockIdx.y, threadIdx.x);
}

// ---------------------------------------------------------------------------
extern "C" void kernel_launch(void* const* d_in, const int* in_sizes, int n_in,
                              void* d_out, int out_size, void* d_ws, size_t ws_size,
                              hipStream_t stream) {
  const float* nbr = (const float*)d_in[0];
  const float* ref = (const float*)d_in[1];
  auto f = [&](int i) { return (const float*)d_in[i]; };

  short* s0 = (short*)d_ws;
  const size_t PM = (size_t)BATCH * HWP * 64;   // 2,359,296 shorts
  short* omB = s0;                              // 7,962,624 shorts
  short* refT = omB + 7962624;
  short* pmA = refT + PM;
  short* pmB = pmA + PM;
  short* pmC = pmB + PM;
  short* pmD = pmC + PM;
  short* pmE = pmD + PM;
  short* pmF = pmE + PM;
  short* pmG = pmF + PM;
  short* wbf = pmG + PM;                        // 589,824
  short* wdcn = wbf + 589824;                   // 147,456
  short* wgc = wdcn + 147456;                   // 188,416
  short* nbrT = (short*)d_out;                  // dead before final write

  // ---- weight prep ----
  prep_om<<<(4 * 147456 + 255) / 256, 256, 0, stream>>>(f(6), f(18), f(30), f(38), wbf);
  prep_dcnw<<<(4 * 36864 + 255) / 256, 256, 0, stream>>>(f(8), f(20), f(32), f(40), wdcn);

  static const int gSrc[12] = {2, 4, 10, 12, 14, 16, 22, 24, 26, 28, 34, 36};
  static const int gCat[12] = {1, 0, 1, 1, 0, 1, 1, 1, 0, 1, 1, 0};
  GwArgs ga;
  int gb = 0;
  const short* wg[12];
  for (int t = 0; t < 12; ++t) {
    ga.src[t] = f(gSrc[t]);
    ga.cat[t] = gCat[t];
    ga.base[t] = gb;
    wg[t] = wgc + gb;
    gb += gCat[t] ? 18432 : 10240;
  }
  ga.base[12] = gb;  // 188,416
  prep_gw<<<(gb + 255) / 256, 256, 0, stream>>>(ga, wgc);

  short* wbf_l3 = wbf;
  short* wbf_l2 = wbf + 147456;
  short* wbf_l1 = wbf + 2 * 147456;
  short* wbf_cas = wbf + 3 * 147456;
  short* wd_l3 = wdcn;
  short* wd_l2 = wdcn + 36864;
  short* wd_l1 = wdcn + 2 * 36864;
  short* wd_cas = wdcn + 3 * 36864;

  dim3 gcGrid(288, BATCH);
  dim3 oc1Grid(288, BATCH, 3);
  dim3 omgcGrid(432, BATCH);
  dim3 dcngcGrid(576, BATCH);
  dim3 omGrid(144, BATCH);
  dim3 dfGrid(288, BATCH);
  dim3 trGrid(HWP / 64, BATCH, 2), trBlk(64, 4);

  transpose_bf16<<<trGrid, trBlk, 0, stream>>>(nbr, nbrT, ref, refT);

  // ---- merged oc1 convs (l3->pmA, l2->pmF, l1->pmG) ----
  Oc1Args oa;
  oa.W[0] = wg[0]; oa.bias[0] = f(3);  oa.out[0] = pmA;
  oa.W[1] = wg[2]; oa.bias[1] = f(11); oa.out[1] = pmF;
  oa.W[2] = wg[6]; oa.bias[2] = f(23); oa.out[2] = pmG;
  gconv_oc1x3<<<oc1Grid, 256, 0, stream>>>(nbrT, refT, oa);

  // ---- l3-oc2 ----
  gconv_mfma<false, true><<<gcGrid, 256, 0, stream>>>(pmA, nullptr, wg[1], f(5), pmB);
  // pmB = to_l3

  // ---- M1: om_l3 || l2-oc2 (cat pmF,pmB -> pmD) ----
  om_gc<5><<<omgcGrid, 256, 0, stream>>>(pmB, wbf_l3, f(7), omB,
                                         pmF, pmB, wg[3], f(13), pmD);
  // ---- M2: dcn_l3 (lrelu -> pmC=tf_l3) || l2-oc3 (pmD -> pmE=to_l2) ----
  dcn_gc<5, true><<<dcngcGrid, 256, 0, stream>>>(nbrT, omB, wd_l3, f(9), pmC,
                                                 pmD, wg[4], f(15), pmE);
  // ---- M3: om_l2 || l1-oc2 (cat pmG,pmE -> pmB) ----
  om_gc<3><<<omgcGrid, 256, 0, stream>>>(pmE, wbf_l2, f(19), omB,
                                         pmG, pmE, wg[7], f(25), pmB);
  // ---- M4: dcn_l2 (no lrelu -> pmD) || l1-oc3 (pmB -> pmF) ----
  dcn_gc<3, false><<<dcngcGrid, 256, 0, stream>>>(nbrT, omB, wd_l2, f(21), pmD,
                                                  pmB, wg[8], f(27), pmF);
  // ---- M5: om_l1 (pmF) || l2-fc (cat pmD,pmC -> pmA=tf_l2) ----
  om_gc<1><<<omgcGrid, 256, 0, stream>>>(pmF, wbf_l1, f(31), omB,
                                         pmD, pmC, wg[5], f(17), pmA);
  // ---- dcn_l1 (no lrelu -> pmE) ----
  dcn_fused<1, false, true><<<dfGrid, 256, 0, stream>>>(nbrT, omB, wd_l1, f(33), pmE);
  // ---- l1-fc (cat pmE,pmA -> pmB = feat, no lrelu); nbrT now dead ----
  gconv_mfma<true, false><<<gcGrid, 256, 0, stream>>>(pmE, pmA, wg[9], f(29), pmB);

  // ---- cascade ----
  gconv_mfma<true, true><<<gcGrid, 256, 0, stream>>>(pmB, refT, wg[10], f(35), pmC);
  gconv_mfma<false, true><<<gcGrid, 256, 0, stream>>>(pmC, nullptr, wg[11], f(37), pmD);
  omconv_mfma<1><<<omGrid, 256, 0, stream>>>(pmD, wbf_cas, f(39), omB);
  dcn_fused<1, true, false><<<dfGrid, 256, 0, stream>>>(pmB, omB, wd_cas, f(41), (float*)d_out);
}

// Round 7
// 496.119 us; speedup vs baseline: 1.3140x; 1.0184x over previous
//
#include <hip/hip_runtime.h>

#define BATCH 4
#define NFEAT 64
#define DGRP 8
#define HH 96
#define WW 96
#define HWP (HH*WW)

typedef short short4a __attribute__((ext_vector_type(4)));
typedef short short8 __attribute__((ext_vector_type(8)));
typedef float f32x4 __attribute__((ext_vector_type(4)));
typedef float f32x16 __attribute__((ext_vector_type(16)));

__device__ inline short f2bf(float f) {
  union { float f; unsigned u; } v; v.f = f;
  unsigned r = v.u + 0x7fff + ((v.u >> 16) & 1);
  return (short)(r >> 16);
}
__device__ inline float bf2f(short s) {
  return __uint_as_float(((unsigned)(unsigned short)s) << 16);
}

// Raw barrier that does NOT drain vmcnt (T14 prerequisite).
__device__ __forceinline__ void barrier_keep_vmcnt() {
  asm volatile("s_waitcnt lgkmcnt(0)" ::: "memory");
  __builtin_amdgcn_s_barrier();
  asm volatile("" ::: "memory");
}

// ---------------------------------------------------------------------------
// Weight-prep element functions (proven R6/R7 shuffles).
// ---------------------------------------------------------------------------
struct GwArgs {
  const float* src[12];
  int cat[12];
  int base[13];
};

__device__ __forceinline__ void prep_om_elem(
    int gid, const float* const* s4, short* __restrict__ dst) {
  int t = gid / 147456, r = gid % 147456;
  int tile = r / 18432, r2 = r % 18432;
  int kk = r2 / 512, r3 = r2 % 512;
  int lane = r3 / 8, j = r3 % 8;
  int col = lane & 31, half = lane >> 5;
  int oc = tile * 32 + col;
  int k = kk * 16 + half * 8 + j;
  int p = k >> 6, c = k & 63;
  float v = (oc < 216) ? s4[t][(size_t)oc * 576 + c * 9 + p] : 0.f;
  dst[gid] = f2bf(v);
}

__device__ __forceinline__ void prep_dcnw_elem(
    int gid, const float* const* s4, short* __restrict__ dst) {
  int t = gid / 36864, r = gid % 36864;
  int tile = r / 18432, r2 = r % 18432;
  int kk = r2 / 512, r3 = r2 % 512;
  int lane = r3 / 8, j = r3 % 8;
  int col = lane & 31, half = lane >> 5;
  int oc = tile * 32 + col;
  int k = kk * 16 + half * 8 + j;
  int p = k >> 6, c = k & 63;
  dst[gid] = f2bf(s4[t][(size_t)oc * 576 + c * 9 + p]);
}

__device__ __forceinline__ void prep_gw_elem(
    int gid, const GwArgs& a, short* __restrict__ dst) {
  int t = 0;
  while (gid >= a.base[t + 1]) ++t;
  int r = gid - a.base[t];
  const float* s = a.src[t];
  const int tsz = a.cat[t] ? 4608 : 2560;
  int tile = r / tsz, r2 = r % tsz;
  int kk = r2 / 512, r3 = r2 % 512;
  int lane = r3 >> 3, j = r3 & 7;
  int m = lane & 15, quad = lane >> 4;
  int oc = tile * 16 + m;
  int j32 = quad * 8 + j;
  float val = 0.f;
  if (a.cat[t]) {
    int gsel = j32 >> 4, ssel = (j32 >> 3) & 1, ch8 = j32 & 7;
    if (gsel == (m >> 3)) val = s[oc * 144 + (2 * ch8 + ssel) * 9 + kk];
  } else {
    int tapsel = j32 >> 4, gsel = (j32 >> 3) & 1, ch8 = j32 & 7;
    int p = 2 * kk + tapsel;
    if (p < 9 && gsel == (m >> 3)) val = s[oc * 72 + ch8 * 9 + p];
  }
  dst[gid] = f2bf(val);
}

// ---------------------------------------------------------------------------
// Fused prep dispatch (R14): transpose (1152 blocks) + om-prep + dcnw-prep +
// gw-prep (3616 blocks) in ONE launch — all mutually independent.
// ---------------------------------------------------------------------------
struct PrepArgs {
  const float* nbr; const float* ref;
  short* nbrT; short* refT;
  const float* omS[4]; short* wbf;
  const float* dwS[4]; short* wdcn;
  GwArgs gw; short* wgc;
};

__global__ __launch_bounds__(256) void prep_fused(PrepArgs a) {
  __shared__ float s[64][65];
  const int bx = blockIdx.x;
  const int lid = threadIdx.x;
  if (bx < 1152) {
    // transpose: x = bx%144, b = (bx/144)&3, z = bx/576
    const int x = bx % 144, b = (bx / 144) & 3, z = bx / 576;
    const float* in = z ? a.ref : a.nbr;
    short* out = z ? a.refT : a.nbrT;
    const int p0 = x * 64;
    const int tx = lid & 63, ty = lid >> 6;
    for (int c = ty; c < 64; c += 4)
      s[c][tx] = in[((size_t)b * NFEAT + c) * HWP + p0 + tx];
    __syncthreads();
    for (int p = ty; p < 64; p += 4)
      out[((size_t)b * HWP + p0 + p) * NFEAT + tx] = f2bf(s[tx][p]);
  } else {
    const int gid = (bx - 1152) * 256 + lid;
    if (gid < 589824) prep_om_elem(gid, a.omS, a.wbf);
    else if (gid < 737280) prep_dcnw_elem(gid - 589824, a.dwS, a.wdcn);
    else if (gid < 925696) prep_gw_elem(gid - 737280, a.gw, a.wgc);
  }
}

// ---------------------------------------------------------------------------
// Grouped 3x3 conv body (proven R7 direct-load).  Flat-256 lid.
// ---------------------------------------------------------------------------
template <bool CAT, bool LRELU>
__device__ __forceinline__ void gconv_body(
    const short* __restrict__ in0, const short* __restrict__ in1,
    const short* __restrict__ Wsh, const float* __restrict__ bias,
    short* __restrict__ out, int pixbase, int b, int lid) {
  const int lane = lid & 63, t = lid >> 6;
  const int n = lane & 15, quad = lane >> 4;
  constexpr int NKK = CAT ? 9 : 5;

  short8 A[NKK];
#pragma unroll
  for (int kk = 0; kk < NKK; ++kk)
    A[kk] = *(const short8*)(Wsh + ((size_t)(t * NKK + kk) * 64 + lane) * 8);

  const short* sb;
  if (CAT) {
    sb = ((quad & 1) ? in1 : in0) + (size_t)b * HWP * 64 + (2 * t + (quad >> 1)) * 8;
  } else {
    sb = in0 + (size_t)b * HWP * 64 + (2 * t + (quad & 1)) * 8;
  }

  f32x4 acc[2] = {};
#pragma unroll
  for (int nt = 0; nt < 2; ++nt) {
    const int pix = pixbase + nt * 16 + n;
    const int yp = pix / WW, xp = pix % WW;
#pragma unroll
    for (int kk = 0; kk < NKK; ++kk) {
      const int p = CAT ? kk : (2 * kk + (quad >> 1));
      short8 B = {0, 0, 0, 0, 0, 0, 0, 0};
      if (p < 9) {
        const int sy = yp + p / 3 - 1, sx = xp + p % 3 - 1;
        if (((unsigned)sy < (unsigned)HH) && ((unsigned)sx < (unsigned)WW))
          B = *(const short8*)(sb + (size_t)(sy * WW + sx) * 64);
      }
      acc[nt] = __builtin_amdgcn_mfma_f32_16x16x32_bf16(A[kk], B, acc[nt], 0, 0, 0);
    }
  }

  const int ocb = t * 16 + quad * 4;
  const float b0 = bias[ocb], b1 = bias[ocb + 1], b2 = bias[ocb + 2], b3 = bias[ocb + 3];
#pragma unroll
  for (int nt = 0; nt < 2; ++nt) {
    float v0 = acc[nt][0] + b0, v1 = acc[nt][1] + b1;
    float v2 = acc[nt][2] + b2, v3 = acc[nt][3] + b3;
    if (LRELU) {
      v0 = (v0 >= 0.f) ? v0 : 0.1f * v0;
      v1 = (v1 >= 0.f) ? v1 : 0.1f * v1;
      v2 = (v2 >= 0.f) ? v2 : 0.1f * v2;
      v3 = (v3 >= 0.f) ? v3 : 0.1f * v3;
    }
    short4a pk = {f2bf(v0), f2bf(v1), f2bf(v2), f2bf(v3)};
    *(short4a*)(out + ((size_t)b * HWP + pixbase + nt * 16 + n) * 64 + ocb) = pk;
  }
}

template <bool CAT, bool LRELU>
__global__ __launch_bounds__(256) void gconv_mfma(
    const short* __restrict__ in0, const short* __restrict__ in1,
    const short* __restrict__ Wsh, const float* __restrict__ bias,
    short* __restrict__ out) {
  gconv_body<CAT, LRELU>(in0, in1, Wsh, bias, out, blockIdx.x * 32, blockIdx.y,
                         threadIdx.x);
}

// Merged dispatch for the 3 independent oc1 convs (all CAT+LRELU).
struct Oc1Args {
  const short* W[3];
  const float* bias[3];
  short* out[3];
};

__global__ __launch_bounds__(256) void gconv_oc1x3(
    const short* __restrict__ in0, const short* __restrict__ in1, Oc1Args a) {
  const int job = blockIdx.z;
  gconv_body<true, true>(in0, in1, a.W[job], a.bias[job], a.out[job],
                         blockIdx.x * 32, blockIdx.y, threadIdx.x);
}

// ---------------------------------------------------------------------------
// Offset/mask conv body (R14): 32-px tiles (was 64) to cut LDS 41.5->20.7KB
// (3 -> 7 blocks/CU) with grid 576 -> 1152.  Per-wave ILP preserved (2
// independent acc chains); T14 async-stage kept.  Slot<->kk mapping is
// row-count-invariant (verified against prep_om layout).
// ---------------------------------------------------------------------------
#define BPITCH 324
template <int D>
__device__ __forceinline__ void omconv_body(
    short* Bs,
    const short* __restrict__ pixT, const short* __restrict__ Wsh,
    const float* __restrict__ bias, short* __restrict__ out,
    int xblk, int b, int lid) {
  const int lane = lid & 63;
  const int w = lid >> 6;
  const int col = lane & 31, half = lane >> 5;
  const int pixbase = xblk * 32;

  const short* aP0 = Wsh + ((size_t)(w * 36) * 64) * 8 + (size_t)lane * 8;
  const short* aP1 = Wsh + ((size_t)((w + 4) * 36) * 64) * 8 + (size_t)lane * 8;
  const short* pixb = pixT + (size_t)b * HWP * 64;

  f32x16 acc00 = {}, acc10 = {};

  // ---- stage phase-0 taps (p 0..4) for 32 rows: 1280 chunks, 5/thread ----
  for (int i = lid; i < 32 * 5 * 8; i += 256) {
    int row = i / 40, q = i % 40;
    int p = q >> 3, c8 = q & 7;
    int pix = pixbase + row;
    int yp = pix / WW, xp = pix % WW;
    int sy = yp + (p / 3 - 1) * D, sx = xp + (p % 3 - 1) * D;
    short4a lo = {0, 0, 0, 0}, hi = {0, 0, 0, 0};
    if (((unsigned)sy < (unsigned)HH) && ((unsigned)sx < (unsigned)WW)) {
      const short* src = pixb + (size_t)(sy * WW + sx) * 64 + c8 * 8;
      lo = *(const short4a*)src;
      hi = *(const short4a*)(src + 4);
    }
    short* dst = Bs + row * BPITCH + q * 8;
    *(short4a*)dst = lo;
    *(short4a*)(dst + 4) = hi;
  }

  // ---- T14: issue phase-1 tap loads (p 5..8) early: 1024 chunks, 4/thread ----
  short4a p1lo[4], p1hi[4];
  int p1dst[4];
#pragma unroll
  for (int idx = 0; idx < 4; ++idx) {
    int i = lid + idx * 256;               // 0..1023 = 32*4*8
    int row = i / 32, q = i % 32;
    int p = 5 + (q >> 3), c8 = q & 7;
    int pix = pixbase + row;
    int yp = pix / WW, xp = pix % WW;
    int sy = yp + (p / 3 - 1) * D, sx = xp + (p % 3 - 1) * D;
    short4a lo = {0, 0, 0, 0}, hi = {0, 0, 0, 0};
    if (((unsigned)sy < (unsigned)HH) && ((unsigned)sx < (unsigned)WW)) {
      const short* src = pixb + (size_t)(sy * WW + sx) * 64 + c8 * 8;
      lo = *(const short4a*)src;
      hi = *(const short4a*)(src + 4);
    }
    p1lo[idx] = lo;
    p1hi[idx] = hi;
    p1dst[idx] = row * BPITCH + q * 8;
  }
  barrier_keep_vmcnt();   // stage-0 LDS visible; phase-1 loads stay in flight

  // ---- MFMA phase 0: kk 0..19 ----
#pragma unroll 4
  for (int kk = 0; kk < 20; ++kk) {
    short8 A0 = *(const short8*)(aP0 + (size_t)kk * 512);
    short8 A1 = *(const short8*)(aP1 + (size_t)kk * 512);
    const short* b0 = Bs + col * BPITCH + kk * 16 + half * 8;
    short4a l0 = *(const short4a*)b0, h0 = *(const short4a*)(b0 + 4);
    short8 B0 = {l0[0], l0[1], l0[2], l0[3], h0[0], h0[1], h0[2], h0[3]};
    acc00 = __builtin_amdgcn_mfma_f32_32x32x16_bf16(A0, B0, acc00, 0, 0, 0);
    acc10 = __builtin_amdgcn_mfma_f32_32x32x16_bf16(A1, B0, acc10, 0, 0, 0);
  }
  barrier_keep_vmcnt();   // all phase-0 Bs reads done before overwrite

  // ---- write phase-1 regs to LDS ----
#pragma unroll
  for (int idx = 0; idx < 4; ++idx) {
    short* dst = Bs + p1dst[idx];
    *(short4a*)dst = p1lo[idx];
    *(short4a*)(dst + 4) = p1hi[idx];
  }
  barrier_keep_vmcnt();   // phase-1 LDS visible

  // ---- MFMA phase 1: kk 20..35 (Bs slots 0..15) ----
#pragma unroll 4
  for (int kk = 0; kk < 16; ++kk) {
    const int kkg = 20 + kk;
    short8 A0 = *(const short8*)(aP0 + (size_t)kkg * 512);
    short8 A1 = *(const short8*)(aP1 + (size_t)kkg * 512);
    const short* b0 = Bs + col * BPITCH + kk * 16 + half * 8;
    short4a l0 = *(const short4a*)b0, h0 = *(const short4a*)(b0 + 4);
    short8 B0 = {l0[0], l0[1], l0[2], l0[3], h0[0], h0[1], h0[2], h0[3]};
    acc00 = __builtin_amdgcn_mfma_f32_32x32x16_bf16(A0, B0, acc00, 0, 0, 0);
    acc10 = __builtin_amdgcn_mfma_f32_32x32x16_bf16(A1, B0, acc10, 0, 0, 0);
  }

  const int pix0 = pixbase + col;
#pragma unroll
  for (int r = 0; r < 16; ++r) {
    const int rrow = (r & 3) + 8 * (r >> 2) + 4 * half;
    const int oc0 = w * 32 + rrow;
    const int oc1 = (w + 4) * 32 + rrow;
    out[((size_t)b * 216 + oc0) * HWP + pix0] = f2bf(acc00[r] + bias[oc0]);
    if (oc1 < 216)
      out[((size_t)b * 216 + oc1) * HWP + pix0] = f2bf(acc10[r] + bias[oc1]);
  }
}

template <int D>
__global__ __launch_bounds__(256) void omconv_mfma(
    const short* __restrict__ pixT, const short* __restrict__ Wsh,
    const float* __restrict__ bias, short* __restrict__ out) {
  __shared__ short Bs[32 * BPITCH];
  omconv_body<D>(Bs, pixT, Wsh, bias, out, blockIdx.x, blockIdx.y, threadIdx.x);
}

// ---------------------------------------------------------------------------
// Fused DCN body (proven R8; R14: red aliased into Ls, LDS 45.6->36.9KB,
// 3 -> 4 blocks/CU; one extra barrier separates Ls reads from red writes).
// ---------------------------------------------------------------------------
template <int D, bool LRELU, bool PMOUT>
__device__ __forceinline__ void dcn_body(
    char* smem,
    const short* __restrict__ xT, const short* __restrict__ om,
    const short* __restrict__ Wd, const float* __restrict__ bias,
    void* __restrict__ outv, int pb, int b, int lid) {
  short* Ls = (short*)smem;
  float* red = (float*)smem;   // alias; barrier-separated from Ls reads
  const int tx = lid & 31, ty = lid >> 5;

  {
    const int px = tx, dg = ty;
    const int pix = pb * 32 + px;
    const int yp = pix / WW, xp = pix % WW;
    const size_t bOM = (size_t)b * 216 * HWP;
    const short* xb = xT + (size_t)b * HWP * 64 + dg * 8;
    short* Sp = Ls + (size_t)((dg & 1) * 32 + px) * 8;

#pragma unroll
    for (int k = 0; k < 9; ++k) {
      float dy = bf2f(om[bOM + (size_t)(dg * 18 + 2 * k) * HWP + pix]);
      float dxv = bf2f(om[bOM + (size_t)(dg * 18 + 2 * k + 1) * HWP + pix]);
      float mr = bf2f(om[bOM + (size_t)(144 + dg * 9 + k) * HWP + pix]);
      float m = 1.f / (1.f + __expf(-mr));
      float py = (float)(yp + (k / 3 - 1) * D) + dy;
      float px_ = (float)(xp + (k % 3 - 1) * D) + dxv;
      float y0f = floorf(py), x0f = floorf(px_);
      float ly = py - y0f, lx = px_ - x0f;
      int y0 = (int)y0f, x0 = (int)x0f;
      int y1 = y0 + 1, x1 = x0 + 1;
      bool vy0 = (unsigned)y0 < (unsigned)HH, vy1 = (unsigned)y1 < (unsigned)HH;
      bool vx0 = (unsigned)x0 < (unsigned)WW, vx1 = (unsigned)x1 < (unsigned)WW;
      int cy0 = min(max(y0, 0), HH - 1), cy1 = min(max(y1, 0), HH - 1);
      int cx0 = min(max(x0, 0), WW - 1), cx1 = min(max(x1, 0), WW - 1);
      float w00 = (vy0 && vx0) ? (1.f - ly) * (1.f - lx) * m : 0.f;
      float w01 = (vy0 && vx1) ? (1.f - ly) * lx * m : 0.f;
      float w10 = (vy1 && vx0) ? ly * (1.f - lx) * m : 0.f;
      float w11 = (vy1 && vx1) ? ly * lx * m : 0.f;
      short8 s00 = *(const short8*)(xb + (size_t)(cy0 * WW + cx0) * 64);
      short8 s01 = *(const short8*)(xb + (size_t)(cy0 * WW + cx1) * 64);
      short8 s10 = *(const short8*)(xb + (size_t)(cy1 * WW + cx0) * 64);
      short8 s11 = *(const short8*)(xb + (size_t)(cy1 * WW + cx1) * 64);
      short8 pk;
#pragma unroll
      for (int cl = 0; cl < 8; ++cl) {
        float v = w00 * bf2f(s00[cl]) + w01 * bf2f(s01[cl]) +
                  w10 * bf2f(s10[cl]) + w11 * bf2f(s11[cl]);
        pk[cl] = f2bf(v);
      }
      const int kk = k * 4 + (dg >> 1);
      *(short8*)(Sp + (size_t)kk * 512) = pk;
    }
  }
  __syncthreads();

  const int lane = lid & 63, w = lid >> 6;
  const int col = lane & 31, half = lane >> 5;
  const int octile = w & 1, kh = w >> 1;
  const int pix = pb * 32 + col;

  const short* aP = Wd + ((size_t)(octile * 36) * 64 + lane) * 8;
  const short* bP = Ls + (size_t)lane * 8;

  f32x16 acc = {};
#pragma unroll 6
  for (int kk = 0; kk < 18; ++kk) {
    const int kkg = kh * 18 + kk;
    short8 A = *(const short8*)(aP + (size_t)kkg * 512);
    short8 B = *(const short8*)(bP + (size_t)kkg * 512);
    acc = __builtin_amdgcn_mfma_f32_32x32x16_bf16(A, B, acc, 0, 0, 0);
  }
  __syncthreads();   // ALL waves' Ls reads complete before red aliases it

  if (kh == 1) {
#pragma unroll
    for (int r = 0; r < 16; ++r) red[((size_t)octile * 64 + lane) * 17 + r] = acc[r];
  }
  __syncthreads();
  if (kh == 0) {
    const float* rp = red + ((size_t)octile * 64 + lane) * 17;
    if (PMOUT) {
      short* out = (short*)outv;
#pragma unroll
      for (int rg = 0; rg < 4; ++rg) {
        short4a pk;
#pragma unroll
        for (int i = 0; i < 4; ++i) {
          const int r = rg * 4 + i;
          const int oc = octile * 32 + i + 8 * rg + 4 * half;
          float v = acc[r] + rp[r] + bias[oc];
          if (LRELU) v = (v >= 0.f) ? v : 0.1f * v;
          pk[i] = f2bf(v);
        }
        *(short4a*)(out + ((size_t)b * HWP + pix) * 64 + octile * 32 + 8 * rg + 4 * half) = pk;
      }
    } else {
      float* out = (float*)outv;
#pragma unroll
      for (int r = 0; r < 16; ++r) {
        const int oc = octile * 32 + (r & 3) + 8 * (r >> 2) + 4 * half;
        float v = acc[r] + rp[r] + bias[oc];
        if (LRELU) v = (v >= 0.f) ? v : 0.1f * v;
        out[((size_t)b * NFEAT + oc) * HWP + pix] = v;
      }
    }
  }
}

template <int D, bool LRELU, bool PMOUT>
__global__ __launch_bounds__(256) void dcn_fused(
    const short* __restrict__ xT, const short* __restrict__ om,
    const short* __restrict__ Wd, const float* __restrict__ bias,
    void* __restrict__ outv) {
  __shared__ __align__(16) char smem[36864];
  dcn_body<D, LRELU, PMOUT>(smem, xT, om, Wd, bias, outv,
                            blockIdx.x, blockIdx.y, threadIdx.x);
}

// ---------------------------------------------------------------------------
// Fat dispatches (R13): co-schedule om / dcn with an INDEPENDENT gconv.
// ---------------------------------------------------------------------------
template <int D>
__global__ __launch_bounds__(256) void om_gc(
    const short* __restrict__ pixT, const short* __restrict__ Wom,
    const float* __restrict__ obias, short* __restrict__ omOut,
    const short* __restrict__ g0, const short* __restrict__ g1,
    const short* __restrict__ gW, const float* __restrict__ gb,
    short* __restrict__ gout) {
  __shared__ short Bs[32 * BPITCH];
  if (blockIdx.x < 288)
    omconv_body<D>(Bs, pixT, Wom, obias, omOut, blockIdx.x, blockIdx.y, threadIdx.x);
  else
    gconv_body<true, true>(g0, g1, gW, gb, gout, (blockIdx.x - 288) * 32,
                           blockIdx.y, threadIdx.x);
}

template <int D, bool DLRELU>
__global__ __launch_bounds__(256) void dcn_gc(
    const short* __restrict__ xT, const short* __restrict__ om,
    const short* __restrict__ Wd, const float* __restrict__ dbias,
    short* __restrict__ dout,
    const short* __restrict__ g0, const short* __restrict__ gW,
    const float* __restrict__ gb, short* __restrict__ gout) {
  __shared__ __align__(16) char smem[36864];
  if (blockIdx.x < 288)
    dcn_body<D, DLRELU, true>(smem, xT, om, Wd, dbias, dout,
                              blockIdx.x, blockIdx.y, threadIdx.x);
  else
    gconv_body<false, true>(g0, nullptr, gW, gb, gout, (blockIdx.x - 288) * 32,
                            blockIdx.y, threadIdx.x);
}

// ---------------------------------------------------------------------------
extern "C" void kernel_launch(void* const* d_in, const int* in_sizes, int n_in,
                              void* d_out, int out_size, void* d_ws, size_t ws_size,
                              hipStream_t stream) {
  const float* nbr = (const float*)d_in[0];
  const float* ref = (const float*)d_in[1];
  auto f = [&](int i) { return (const float*)d_in[i]; };

  short* s0 = (short*)d_ws;
  const size_t PM = (size_t)BATCH * HWP * 64;   // 2,359,296 shorts
  short* omB = s0;                              // 7,962,624 shorts
  short* refT = omB + 7962624;
  short* pmA = refT + PM;
  short* pmB = pmA + PM;
  short* pmC = pmB + PM;
  short* pmD = pmC + PM;
  short* pmE = pmD + PM;
  short* pmF = pmE + PM;
  short* pmG = pmF + PM;
  short* wbf = pmG + PM;                        // 589,824
  short* wdcn = wbf + 589824;                   // 147,456
  short* wgc = wdcn + 147456;                   // 188,416
  short* nbrT = (short*)d_out;                  // dead before final write

  // ---- weight prep + transpose, single fused dispatch ----
  static const int gSrc[12] = {2, 4, 10, 12, 14, 16, 22, 24, 26, 28, 34, 36};
  static const int gCat[12] = {1, 0, 1, 1, 0, 1, 1, 1, 0, 1, 1, 0};
  GwArgs ga;
  int gb = 0;
  const short* wg[12];
  for (int t = 0; t < 12; ++t) {
    ga.src[t] = f(gSrc[t]);
    ga.cat[t] = gCat[t];
    ga.base[t] = gb;
    wg[t] = wgc + gb;
    gb += gCat[t] ? 18432 : 10240;
  }
  ga.base[12] = gb;  // 188,416

  PrepArgs pa;
  pa.nbr = nbr; pa.ref = ref; pa.nbrT = nbrT; pa.refT = refT;
  pa.omS[0] = f(6);  pa.omS[1] = f(18); pa.omS[2] = f(30); pa.omS[3] = f(38);
  pa.wbf = wbf;
  pa.dwS[0] = f(8);  pa.dwS[1] = f(20); pa.dwS[2] = f(32); pa.dwS[3] = f(40);
  pa.wdcn = wdcn;
  pa.gw = ga; pa.wgc = wgc;
  prep_fused<<<dim3(4768), 256, 0, stream>>>(pa);

  short* wbf_l3 = wbf;
  short* wbf_l2 = wbf + 147456;
  short* wbf_l1 = wbf + 2 * 147456;
  short* wbf_cas = wbf + 3 * 147456;
  short* wd_l3 = wdcn;
  short* wd_l2 = wdcn + 36864;
  short* wd_l1 = wdcn + 2 * 36864;
  short* wd_cas = wdcn + 3 * 36864;

  dim3 gcGrid(288, BATCH);
  dim3 oc1Grid(288, BATCH, 3);
  dim3 omgcGrid(576, BATCH);
  dim3 dcngcGrid(576, BATCH);
  dim3 omGrid(288, BATCH);
  dim3 dfGrid(288, BATCH);

  // ---- merged oc1 convs (l3->pmA, l2->pmF, l1->pmG) ----
  Oc1Args oa;
  oa.W[0] = wg[0]; oa.bias[0] = f(3);  oa.out[0] = pmA;
  oa.W[1] = wg[2]; oa.bias[1] = f(11); oa.out[1] = pmF;
  oa.W[2] = wg[6]; oa.bias[2] = f(23); oa.out[2] = pmG;
  gconv_oc1x3<<<oc1Grid, 256, 0, stream>>>(nbrT, refT, oa);

  // ---- l3-oc2 ----
  gconv_mfma<false, true><<<gcGrid, 256, 0, stream>>>(pmA, nullptr, wg[1], f(5), pmB);
  // pmB = to_l3

  // ---- M1: om_l3 || l2-oc2 (cat pmF,pmB -> pmD) ----
  om_gc<5><<<omgcGrid, 256, 0, stream>>>(pmB, wbf_l3, f(7), omB,
                                         pmF, pmB, wg[3], f(13), pmD);
  // ---- M2: dcn_l3 (lrelu -> pmC=tf_l3) || l2-oc3 (pmD -> pmE=to_l2) ----
  dcn_gc<5, true><<<dcngcGrid, 256, 0, stream>>>(nbrT, omB, wd_l3, f(9), pmC,
                                                 pmD, wg[4], f(15), pmE);
  // ---- M3: om_l2 || l1-oc2 (cat pmG,pmE -> pmB) ----
  om_gc<3><<<omgcGrid, 256, 0, stream>>>(pmE, wbf_l2, f(19), omB,
                                         pmG, pmE, wg[7], f(25), pmB);
  // ---- M4: dcn_l2 (no lrelu -> pmD) || l1-oc3 (pmB -> pmF) ----
  dcn_gc<3, false><<<dcngcGrid, 256, 0, stream>>>(nbrT, omB, wd_l2, f(21), pmD,
                                                  pmB, wg[8], f(27), pmF);
  // ---- M5: om_l1 (pmF) || l2-fc (cat pmD,pmC -> pmA=tf_l2) ----
  om_gc<1><<<omgcGrid, 256, 0, stream>>>(pmF, wbf_l1, f(31), omB,
                                         pmD, pmC, wg[5], f(17), pmA);
  // ---- dcn_l1 (no lrelu -> pmE) ----
  dcn_fused<1, false, true><<<dfGrid, 256, 0, stream>>>(nbrT, omB, wd_l1, f(33), pmE);
  // ---- l1-fc (cat pmE,pmA -> pmB = feat, no lrelu); nbrT now dead ----
  gconv_mfma<true, false><<<gcGrid, 256, 0, stream>>>(pmE, pmA, wg[9], f(29), pmB);

  // ---- cascade ----
  gconv_mfma<true, true><<<gcGrid, 256, 0, stream>>>(pmB, refT, wg[10], f(35), pmC);
  gconv_mfma<false, true><<<gcGrid, 256, 0, stream>>>(pmC, nullptr, wg[11], f(37), pmD);
  omconv_mfma<1><<<omGrid, 256, 0, stream>>>(pmD, wbf_cas, f(39), omB);
  dcn_fused<1, true, false><<<dfGrid, 256, 0, stream>>>(pmB, omB, wd_cas, f(41), (float*)d_out);
}